// Round 1
// baseline (8642.979 us; speedup 1.0000x reference)
//
#include <hip/hip_runtime.h>
#include <math.h>

#define N_GRAPHS 100

__device__ __forceinline__ float lrelu(float v) { return v >= 0.f ? v : 0.1f * v; }

// ---------------- degrees ----------------
__global__ void k_degrees(const int* __restrict__ src, const int* __restrict__ dst,
                          float* __restrict__ deg_src, float* __restrict__ deg_dst, int E) {
    int i = blockIdx.x * blockDim.x + threadIdx.x;
    if (i < E) {
        atomicAdd(&deg_src[src[i]], 1.0f);
        atomicAdd(&deg_dst[dst[i]], 1.0f);
    }
}

__global__ void k_dinv(float* __restrict__ dsrc, float* __restrict__ ddst, int N) {
    int i = blockIdx.x * blockDim.x + threadIdx.x;
    if (i < N) {
        dsrc[i] = rsqrtf(fmaxf(dsrc[i], 1.0f));
        ddst[i] = rsqrtf(fmaxf(ddst[i], 1.0f));
    }
}

// ---------------- fold W3 @ Wout -> w[128], c = b3.Wout + bout ----------------
__global__ void k_fold_w(const float* __restrict__ W3, const float* __restrict__ b3,
                         const float* __restrict__ Wout, const float* __restrict__ bout,
                         float* __restrict__ w, float* __restrict__ cval) {
    int i = threadIdx.x; // 128 threads
    float s = 0.f;
    for (int j = 0; j < 64; ++j) s += W3[i * 64 + j] * Wout[j];
    w[i] = s;
    if (i == 0) {
        float c = bout[0];
        for (int j = 0; j < 64; ++j) c += b3[j] * Wout[j];
        *cval = c;
    }
}

// ---------------- fused pre-norm + GEMM (in-place safe) ----------------
// PRE==0:  Y[r] = (X[r] * dinv_src[r]) @ W
// PRE==1:  Y[r] = (lrelu(X[r]*dinv_dst[r] + bias) * dinv_src[r]) @ W
template <int PRE>
__global__ __launch_bounds__(256, 2)
void k_gemm128(const float* __restrict__ X, float* __restrict__ Y,
               const float* __restrict__ W, const float* __restrict__ bias,
               const float* __restrict__ dinv_dst, const float* __restrict__ dinv_src,
               int N) {
    __shared__ float Ws[128 * 128];   // 64 KiB
    __shared__ float Xs[32 * 128];    // 16 KiB, XOR-swizzled rows
    const int t = threadIdx.x;
    const int r0 = blockIdx.x * 32;

    for (int i = t; i < 4096; i += 256)
        ((float4*)Ws)[i] = ((const float4*)W)[i];

    for (int i = t; i < 1024; i += 256) {
        int r = i >> 5;              // 0..31
        int c4 = (i & 31) << 2;      // 0,4,...,124
        int row = r0 + r;
        float4 v = make_float4(0.f, 0.f, 0.f, 0.f);
        if (row < N) {
            v = ((const float4*)(X + (size_t)row * 128))[i & 31];
            float ds = dinv_src[row];
            if (PRE) {
                float dd = dinv_dst[row];
                v.x = lrelu(v.x * dd + bias[c4 + 0]) * ds;
                v.y = lrelu(v.y * dd + bias[c4 + 1]) * ds;
                v.z = lrelu(v.z * dd + bias[c4 + 2]) * ds;
                v.w = lrelu(v.w * dd + bias[c4 + 3]) * ds;
            } else {
                v.x *= ds; v.y *= ds; v.z *= ds; v.w *= ds;
            }
        }
        int sw = (r & 7) << 2;
        *(float4*)&Xs[r * 128 + (c4 ^ sw)] = v;
    }
    __syncthreads();

    const int rg = t >> 4;          // 0..15
    const int cg = t & 15;          // 0..15
    const int ra = 2 * rg, rb = 2 * rg + 1;
    const int swa = (ra & 7) << 2, swb = (rb & 7) << 2;
    float acc0[8], acc1[8];
#pragma unroll
    for (int q = 0; q < 8; ++q) { acc0[q] = 0.f; acc1[q] = 0.f; }

#pragma unroll 8
    for (int k = 0; k < 128; ++k) {
        float x0 = Xs[ra * 128 + (k ^ swa)];
        float x1 = Xs[rb * 128 + (k ^ swb)];
        const float4 w0 = *(const float4*)&Ws[k * 128 + 8 * cg];
        const float4 w1 = *(const float4*)&Ws[k * 128 + 8 * cg + 4];
        acc0[0] += x0 * w0.x; acc0[1] += x0 * w0.y; acc0[2] += x0 * w0.z; acc0[3] += x0 * w0.w;
        acc0[4] += x0 * w1.x; acc0[5] += x0 * w1.y; acc0[6] += x0 * w1.z; acc0[7] += x0 * w1.w;
        acc1[0] += x1 * w0.x; acc1[1] += x1 * w0.y; acc1[2] += x1 * w0.z; acc1[3] += x1 * w0.w;
        acc1[4] += x1 * w1.x; acc1[5] += x1 * w1.y; acc1[6] += x1 * w1.z; acc1[7] += x1 * w1.w;
    }

    int rowa = r0 + ra, rowb = r0 + rb;
    if (rowa < N) {
        *(float4*)(Y + (size_t)rowa * 128 + 8 * cg)     = make_float4(acc0[0], acc0[1], acc0[2], acc0[3]);
        *(float4*)(Y + (size_t)rowa * 128 + 8 * cg + 4) = make_float4(acc0[4], acc0[5], acc0[6], acc0[7]);
    }
    if (rowb < N) {
        *(float4*)(Y + (size_t)rowb * 128 + 8 * cg)     = make_float4(acc1[0], acc1[1], acc1[2], acc1[3]);
        *(float4*)(Y + (size_t)rowb * 128 + 8 * cg + 4) = make_float4(acc1[4], acc1[5], acc1[6], acc1[7]);
    }
}

// ---------------- 128-wide scatter-add: A[dst] += T[src] ----------------
__global__ void k_scatter128(const float* __restrict__ T, float* __restrict__ A,
                             const int* __restrict__ src, const int* __restrict__ dst, int E) {
    int tid = blockIdx.x * blockDim.x + threadIdx.x;
    int e = tid >> 5;
    if (e >= E) return;
    int c = (tid & 31) << 2;
    int s = src[e], d = dst[e];
    const float4 v = *(const float4*)(T + (size_t)s * 128 + c);
    float* a = A + (size_t)d * 128 + c;
    atomicAdd(a + 0, v.x);
    atomicAdd(a + 1, v.y);
    atomicAdd(a + 2, v.z);
    atomicAdd(a + 3, v.w);
}

// ---------------- folded conv3+readout: t[n] = dinv_src[n]*(lrelu(A[n]*ddst+b2) . w) ----------------
__global__ void k_node_scalar(const float* __restrict__ A, const float* __restrict__ dinv_dst,
                              const float* __restrict__ dinv_src, const float* __restrict__ bias,
                              const float* __restrict__ w, float* __restrict__ tv, int N) {
    int gtid = blockIdx.x * blockDim.x + threadIdx.x;
    int wid = gtid >> 6;
    int lane = gtid & 63;
    if (wid >= N) return;
    float dd = dinv_dst[wid];
    const float* row = A + (size_t)wid * 128;
    float h0 = lrelu(row[lane] * dd + bias[lane]);
    float h1 = lrelu(row[lane + 64] * dd + bias[lane + 64]);
    float s = h0 * w[lane] + h1 * w[lane + 64];
#pragma unroll
    for (int o = 32; o > 0; o >>= 1) s += __shfl_down(s, o);
    if (lane == 0) tv[wid] = s * dinv_src[wid];
}

// ---------------- scalar scatter: z[dst] += t[src] ----------------
__global__ void k_scatter1(const float* __restrict__ tv, float* __restrict__ z,
                           const int* __restrict__ src, const int* __restrict__ dst, int E) {
    int e = blockIdx.x * blockDim.x + threadIdx.x;
    if (e < E) atomicAdd(&z[dst[e]], tv[src[e]]);
}

// ---------------- per-graph mean (stage 1: block-local bins) ----------------
__global__ void k_graph_reduce(const float* __restrict__ z, const float* __restrict__ dinv_dst,
                               const int* __restrict__ gid, const float* __restrict__ cval,
                               float* __restrict__ gsum, float* __restrict__ gcnt, int N) {
    __shared__ float sb[N_GRAPHS], sc[N_GRAPHS];
    for (int i = threadIdx.x; i < N_GRAPHS; i += blockDim.x) { sb[i] = 0.f; sc[i] = 0.f; }
    __syncthreads();
    int i = blockIdx.x * blockDim.x + threadIdx.x;
    if (i < N) {
        float s = z[i] * dinv_dst[i] + cval[0];
        int g = gid[i];
        atomicAdd(&sb[g], s);
        atomicAdd(&sc[g], 1.f);
    }
    __syncthreads();
    for (int j = threadIdx.x; j < N_GRAPHS; j += blockDim.x) {
        if (sc[j] != 0.f) {
            atomicAdd(&gsum[j], sb[j]);
            atomicAdd(&gcnt[j], sc[j]);
        }
    }
}

__global__ void k_final(const float* __restrict__ gsum, const float* __restrict__ gcnt,
                        float* __restrict__ out) {
    int g = threadIdx.x;
    if (g < N_GRAPHS) out[g] = gsum[g] / fmaxf(gcnt[g], 1.0f);
}

extern "C" void kernel_launch(void* const* d_in, const int* in_sizes, int n_in,
                              void* d_out, int out_size, void* d_ws, size_t ws_size,
                              hipStream_t stream) {
    const float* in_feat = (const float*)d_in[0];
    const float* W1   = (const float*)d_in[1];
    const float* b1   = (const float*)d_in[2];
    const float* W2   = (const float*)d_in[3];
    const float* b2   = (const float*)d_in[4];
    const float* W3   = (const float*)d_in[5];
    const float* b3   = (const float*)d_in[6];
    const float* Wout = (const float*)d_in[7];
    const float* bout = (const float*)d_in[8];
    const int* src = (const int*)d_in[9];
    const int* dst = (const int*)d_in[10];
    const int* gid = (const int*)d_in[11];
    const int N = in_sizes[0] / 128;
    const int E = in_sizes[9];
    float* out = (float*)d_out;

    char* ws = (char*)d_ws;
    size_t off = 0;
    auto alloc = [&](size_t bytes) {
        void* p = ws + off;
        off = (off + bytes + 255) & ~(size_t)255;
        return p;
    };
    float* P     = (float*)alloc((size_t)N * 128 * 4);
    float* Q     = (float*)alloc((size_t)N * 128 * 4);
    float* dsrc  = (float*)alloc((size_t)N * 4);
    float* ddst  = (float*)alloc((size_t)N * 4);
    float* tv    = (float*)alloc((size_t)N * 4);
    float* z     = (float*)alloc((size_t)N * 4);
    float* wfold = (float*)alloc(128 * 4);
    float* cval  = (float*)alloc(4);
    float* gsum  = (float*)alloc(N_GRAPHS * 4);
    float* gcnt  = (float*)alloc(N_GRAPHS * 4);
    (void)ws_size; (void)n_in; (void)out_size;

    hipMemsetAsync(dsrc, 0, (size_t)N * 4, stream);
    hipMemsetAsync(ddst, 0, (size_t)N * 4, stream);
    hipMemsetAsync(z, 0, (size_t)N * 4, stream);
    hipMemsetAsync(gsum, 0, N_GRAPHS * 4, stream);
    hipMemsetAsync(gcnt, 0, N_GRAPHS * 4, stream);

    k_degrees<<<(E + 255) / 256, 256, 0, stream>>>(src, dst, dsrc, ddst, E);
    k_dinv<<<(N + 255) / 256, 256, 0, stream>>>(dsrc, ddst, N);
    k_fold_w<<<1, 128, 0, stream>>>(W3, b3, Wout, bout, wfold, cval);

    const int gblocks = (N + 31) / 32;
    const int sblocks = (int)(((size_t)E * 32 + 255) / 256);

    // layer 1: T1 = (in_feat * dsrc) @ W1 -> P ; A1 = scatter(T1) -> Q
    k_gemm128<0><<<gblocks, 256, 0, stream>>>(in_feat, P, W1, nullptr, nullptr, dsrc, N);
    hipMemsetAsync(Q, 0, (size_t)N * 128 * 4, stream);
    k_scatter128<<<sblocks, 256, 0, stream>>>(P, Q, src, dst, E);

    // layer 2: T2 = (lrelu(A1*ddst + b1) * dsrc) @ W2  (in place on Q) ; A2 -> P
    k_gemm128<1><<<gblocks, 256, 0, stream>>>(Q, Q, W2, b1, ddst, dsrc, N);
    hipMemsetAsync(P, 0, (size_t)N * 128 * 4, stream);
    k_scatter128<<<sblocks, 256, 0, stream>>>(Q, P, src, dst, E);

    // layer 3 (conv2 again): T3 = (lrelu(A2*ddst + b2) * dsrc) @ W2 (in place on P) ; A3 -> Q
    k_gemm128<1><<<gblocks, 256, 0, stream>>>(P, P, W2, b2, ddst, dsrc, N);
    hipMemsetAsync(Q, 0, (size_t)N * 128 * 4, stream);
    k_scatter128<<<sblocks, 256, 0, stream>>>(P, Q, src, dst, E);

    // folded conv3 + readout
    k_node_scalar<<<(N + 3) / 4, 256, 0, stream>>>(Q, ddst, dsrc, b2, wfold, tv, N);
    k_scatter1<<<(E + 255) / 256, 256, 0, stream>>>(tv, z, src, dst, E);
    k_graph_reduce<<<(N + 255) / 256, 256, 0, stream>>>(z, ddst, gid, cval, gsum, gcnt, N);
    k_final<<<1, 128, 0, stream>>>(gsum, gcnt, out);
}

// Round 2
// 942.892 us; speedup vs baseline: 9.1665x; 9.1665x over previous
//
#include <hip/hip_runtime.h>
#include <math.h>

#define N_GRAPHS 100

__device__ __forceinline__ float lrelu(float v) { return v >= 0.f ? v : 0.1f * v; }

// ---------------- degrees (int) ----------------
__global__ void k_degrees(const int* __restrict__ src, const int* __restrict__ dst,
                          int* __restrict__ degs, int* __restrict__ degd, int E) {
    int i = blockIdx.x * blockDim.x + threadIdx.x;
    if (i < E) {
        atomicAdd(&degs[src[i]], 1);
        atomicAdd(&degd[dst[i]], 1);
    }
}

__global__ void k_dinv(const int* __restrict__ degs, const int* __restrict__ degd,
                       float* __restrict__ dsrc, float* __restrict__ ddst, int N) {
    int i = blockIdx.x * blockDim.x + threadIdx.x;
    if (i < N) {
        dsrc[i] = rsqrtf(fmaxf((float)degs[i], 1.0f));
        ddst[i] = rsqrtf(fmaxf((float)degd[i], 1.0f));
    }
}

// ---------------- fold W3 @ Wout -> w[128], c = b3.Wout + bout ----------------
__global__ void k_fold_w(const float* __restrict__ W3, const float* __restrict__ b3,
                         const float* __restrict__ Wout, const float* __restrict__ bout,
                         float* __restrict__ w, float* __restrict__ cval) {
    int i = threadIdx.x; // 128 threads
    float s = 0.f;
    for (int j = 0; j < 64; ++j) s += W3[i * 64 + j] * Wout[j];
    w[i] = s;
    if (i == 0) {
        float c = bout[0];
        for (int j = 0; j < 64; ++j) c += b3[j] * Wout[j];
        *cval = c;
    }
}

// ---------------- exclusive scan over degd -> off (3-kernel) ----------------
// A: per-block (1024 elems) local exclusive offsets + block totals
__global__ void k_scanA(const int* __restrict__ deg, int* __restrict__ off,
                        int* __restrict__ partials, int N) {
    __shared__ int ts[256];
    const int t = threadIdx.x;
    const int base = blockIdx.x * 1024 + t * 4;
    int v0 = (base + 0 < N) ? deg[base + 0] : 0;
    int v1 = (base + 1 < N) ? deg[base + 1] : 0;
    int v2 = (base + 2 < N) ? deg[base + 2] : 0;
    int v3 = (base + 3 < N) ? deg[base + 3] : 0;
    int s = v0 + v1 + v2 + v3;
    ts[t] = s;
    __syncthreads();
    for (int o = 1; o < 256; o <<= 1) {
        int y = (t >= o) ? ts[t - o] : 0;
        __syncthreads();
        ts[t] += y;
        __syncthreads();
    }
    int excl = ts[t] - s;
    if (base + 0 < N) off[base + 0] = excl;
    if (base + 1 < N) off[base + 1] = excl + v0;
    if (base + 2 < N) off[base + 2] = excl + v0 + v1;
    if (base + 3 < N) off[base + 3] = excl + v0 + v1 + v2;
    if (t == 255) partials[blockIdx.x] = ts[255];
}

// B: exclusive scan of block totals (<=256 blocks) in one block
__global__ void k_scanB(int* __restrict__ partials, int nb) {
    __shared__ int ps[256];
    const int t = threadIdx.x;
    int v = (t < nb) ? partials[t] : 0;
    ps[t] = v;
    __syncthreads();
    for (int o = 1; o < 256; o <<= 1) {
        int y = (t >= o) ? ps[t - o] : 0;
        __syncthreads();
        ps[t] += y;
        __syncthreads();
    }
    if (t < nb) partials[t] = ps[t] - v;
}

// C: add scanned block totals; emit cursor copy; write off[N]=E
__global__ void k_scanC(int* __restrict__ off, int* __restrict__ cursor,
                        const int* __restrict__ partials, int N, int E) {
    const int t = threadIdx.x;
    const int base = blockIdx.x * 1024 + t * 4;
    const int add = partials[blockIdx.x];
#pragma unroll
    for (int q = 0; q < 4; ++q) {
        int idx = base + q;
        if (idx < N) {
            int v = off[idx] + add;
            off[idx] = v;
            cursor[idx] = v;
        }
    }
    if (blockIdx.x == 0 && t == 0) off[N] = E;
}

// ---------------- CSR fill: bucket edges by dst ----------------
__global__ void k_csrfill(const int* __restrict__ src, const int* __restrict__ dst,
                          int* __restrict__ cursor, int* __restrict__ csr, int E) {
    int e = blockIdx.x * blockDim.x + threadIdx.x;
    if (e < E) {
        int p = atomicAdd(&cursor[dst[e]], 1);
        csr[p] = src[e];
    }
}

// ---------------- fused pre-norm + GEMM (in-place safe) ----------------
// PRE==0:  Y[r] = (X[r] * dinv_src[r]) @ W
// PRE==1:  Y[r] = (lrelu(X[r]*dinv_dst[r] + bias) * dinv_src[r]) @ W
template <int PRE>
__global__ __launch_bounds__(256, 2)
void k_gemm128(const float* __restrict__ X, float* __restrict__ Y,
               const float* __restrict__ W, const float* __restrict__ bias,
               const float* __restrict__ dinv_dst, const float* __restrict__ dinv_src,
               int N) {
    __shared__ float Ws[128 * 128];   // 64 KiB
    __shared__ float Xs[32 * 128];    // 16 KiB, XOR-swizzled rows
    const int t = threadIdx.x;
    const int r0 = blockIdx.x * 32;

    for (int i = t; i < 4096; i += 256)
        ((float4*)Ws)[i] = ((const float4*)W)[i];

    for (int i = t; i < 1024; i += 256) {
        int r = i >> 5;              // 0..31
        int c4 = (i & 31) << 2;      // 0,4,...,124
        int row = r0 + r;
        float4 v = make_float4(0.f, 0.f, 0.f, 0.f);
        if (row < N) {
            v = ((const float4*)(X + (size_t)row * 128))[i & 31];
            float ds = dinv_src[row];
            if (PRE) {
                float dd = dinv_dst[row];
                v.x = lrelu(v.x * dd + bias[c4 + 0]) * ds;
                v.y = lrelu(v.y * dd + bias[c4 + 1]) * ds;
                v.z = lrelu(v.z * dd + bias[c4 + 2]) * ds;
                v.w = lrelu(v.w * dd + bias[c4 + 3]) * ds;
            } else {
                v.x *= ds; v.y *= ds; v.z *= ds; v.w *= ds;
            }
        }
        int sw = (r & 7) << 2;
        *(float4*)&Xs[r * 128 + (c4 ^ sw)] = v;
    }
    __syncthreads();

    const int rg = t >> 4;          // 0..15
    const int cg = t & 15;          // 0..15
    const int ra = 2 * rg, rb = 2 * rg + 1;
    const int swa = (ra & 7) << 2, swb = (rb & 7) << 2;
    float acc0[8], acc1[8];
#pragma unroll
    for (int q = 0; q < 8; ++q) { acc0[q] = 0.f; acc1[q] = 0.f; }

#pragma unroll 8
    for (int k = 0; k < 128; ++k) {
        float x0 = Xs[ra * 128 + (k ^ swa)];
        float x1 = Xs[rb * 128 + (k ^ swb)];
        const float4 w0 = *(const float4*)&Ws[k * 128 + 8 * cg];
        const float4 w1 = *(const float4*)&Ws[k * 128 + 8 * cg + 4];
        acc0[0] += x0 * w0.x; acc0[1] += x0 * w0.y; acc0[2] += x0 * w0.z; acc0[3] += x0 * w0.w;
        acc0[4] += x0 * w1.x; acc0[5] += x0 * w1.y; acc0[6] += x0 * w1.z; acc0[7] += x0 * w1.w;
        acc1[0] += x1 * w0.x; acc1[1] += x1 * w0.y; acc1[2] += x1 * w0.z; acc1[3] += x1 * w0.w;
        acc1[4] += x1 * w1.x; acc1[5] += x1 * w1.y; acc1[6] += x1 * w1.z; acc1[7] += x1 * w1.w;
    }

    int rowa = r0 + ra, rowb = r0 + rb;
    if (rowa < N) {
        *(float4*)(Y + (size_t)rowa * 128 + 8 * cg)     = make_float4(acc0[0], acc0[1], acc0[2], acc0[3]);
        *(float4*)(Y + (size_t)rowa * 128 + 8 * cg + 4) = make_float4(acc0[4], acc0[5], acc0[6], acc0[7]);
    }
    if (rowb < N) {
        *(float4*)(Y + (size_t)rowb * 128 + 8 * cg)     = make_float4(acc1[0], acc1[1], acc1[2], acc1[3]);
        *(float4*)(Y + (size_t)rowb * 128 + 8 * cg + 4) = make_float4(acc1[4], acc1[5], acc1[6], acc1[7]);
    }
}

// ---------------- CSR gather-aggregate: Y[n] = sum_{e: dst=n} T[src[e]] ----------------
// one 32-lane half-wave per node; lane owns 4 contiguous floats
__global__ __launch_bounds__(256)
void k_gather128(const float* __restrict__ T, float* __restrict__ Y,
                 const int* __restrict__ csr, const int* __restrict__ off, int N) {
    int n = blockIdx.x * (blockDim.x >> 5) + (threadIdx.x >> 5);
    if (n >= N) return;
    const int lane = threadIdx.x & 31;
    const int c = lane << 2;
    int j = off[n];
    const int jend = off[n + 1];
    float4 acc = make_float4(0.f, 0.f, 0.f, 0.f);
    for (; j + 1 < jend; j += 2) {
        int a = csr[j], b = csr[j + 1];
        float4 va = *(const float4*)(T + (size_t)a * 128 + c);
        float4 vb = *(const float4*)(T + (size_t)b * 128 + c);
        acc.x += va.x + vb.x;
        acc.y += va.y + vb.y;
        acc.z += va.z + vb.z;
        acc.w += va.w + vb.w;
    }
    if (j < jend) {
        int a = csr[j];
        float4 va = *(const float4*)(T + (size_t)a * 128 + c);
        acc.x += va.x; acc.y += va.y; acc.z += va.z; acc.w += va.w;
    }
    *(float4*)(Y + (size_t)n * 128 + c) = acc;
}

// ---------------- folded conv3+readout: tv[n] = dinv_src[n]*(lrelu(A[n]*ddst+b2) . w) ----------------
__global__ void k_node_scalar(const float* __restrict__ A, const float* __restrict__ dinv_dst,
                              const float* __restrict__ dinv_src, const float* __restrict__ bias,
                              const float* __restrict__ w, float* __restrict__ tv, int N) {
    int gtid = blockIdx.x * blockDim.x + threadIdx.x;
    int wid = gtid >> 6;
    int lane = gtid & 63;
    if (wid >= N) return;
    float dd = dinv_dst[wid];
    const float* row = A + (size_t)wid * 128;
    float h0 = lrelu(row[lane] * dd + bias[lane]);
    float h1 = lrelu(row[lane + 64] * dd + bias[lane + 64]);
    float s = h0 * w[lane] + h1 * w[lane + 64];
#pragma unroll
    for (int o = 32; o > 0; o >>= 1) s += __shfl_down(s, o);
    if (lane == 0) tv[wid] = s * dinv_src[wid];
}

// ---------------- final: z[n]=sum tv[csr], s=z*ddst+c, per-graph mean bins ----------------
__global__ void k_gather_final(const float* __restrict__ tv, const int* __restrict__ csr,
                               const int* __restrict__ off, const float* __restrict__ ddst,
                               const int* __restrict__ gid, const float* __restrict__ cval,
                               float* __restrict__ gsum, float* __restrict__ gcnt, int N) {
    __shared__ float sb[N_GRAPHS], sc[N_GRAPHS];
    for (int i = threadIdx.x; i < N_GRAPHS; i += blockDim.x) { sb[i] = 0.f; sc[i] = 0.f; }
    __syncthreads();
    int n = blockIdx.x * blockDim.x + threadIdx.x;
    if (n < N) {
        int j = off[n], jend = off[n + 1];
        float z = 0.f;
        for (; j < jend; ++j) z += tv[csr[j]];
        float s = z * ddst[n] + cval[0];
        int g = gid[n];
        atomicAdd(&sb[g], s);
        atomicAdd(&sc[g], 1.f);
    }
    __syncthreads();
    for (int j = threadIdx.x; j < N_GRAPHS; j += blockDim.x) {
        if (sc[j] != 0.f) {
            atomicAdd(&gsum[j], sb[j]);
            atomicAdd(&gcnt[j], sc[j]);
        }
    }
}

__global__ void k_final(const float* __restrict__ gsum, const float* __restrict__ gcnt,
                        float* __restrict__ out) {
    int g = threadIdx.x;
    if (g < N_GRAPHS) out[g] = gsum[g] / fmaxf(gcnt[g], 1.0f);
}

extern "C" void kernel_launch(void* const* d_in, const int* in_sizes, int n_in,
                              void* d_out, int out_size, void* d_ws, size_t ws_size,
                              hipStream_t stream) {
    const float* in_feat = (const float*)d_in[0];
    const float* W1   = (const float*)d_in[1];
    const float* b1   = (const float*)d_in[2];
    const float* W2   = (const float*)d_in[3];
    const float* b2   = (const float*)d_in[4];
    const float* W3   = (const float*)d_in[5];
    const float* b3   = (const float*)d_in[6];
    const float* Wout = (const float*)d_in[7];
    const float* bout = (const float*)d_in[8];
    const int* src = (const int*)d_in[9];
    const int* dst = (const int*)d_in[10];
    const int* gid = (const int*)d_in[11];
    const int N = in_sizes[0] / 128;
    const int E = in_sizes[9];
    float* out = (float*)d_out;

    char* ws = (char*)d_ws;
    size_t woff = 0;
    auto alloc = [&](size_t bytes) {
        void* p = ws + woff;
        woff = (woff + bytes + 255) & ~(size_t)255;
        return p;
    };
    float* P     = (float*)alloc((size_t)N * 128 * 4);
    float* Q     = (float*)alloc((size_t)N * 128 * 4);
    int*   csr   = (int*)alloc((size_t)E * 4);
    int*   degs  = (int*)alloc((size_t)N * 4);
    int*   degd  = (int*)alloc((size_t)N * 4);
    int*   off   = (int*)alloc((size_t)(N + 1) * 4);
    int*   cursor= (int*)alloc((size_t)N * 4);
    int*   partials = (int*)alloc(256 * 4);
    float* dsrc  = (float*)alloc((size_t)N * 4);
    float* ddst  = (float*)alloc((size_t)N * 4);
    float* tv    = (float*)alloc((size_t)N * 4);
    float* wfold = (float*)alloc(128 * 4);
    float* cval  = (float*)alloc(4);
    float* gsum  = (float*)alloc(N_GRAPHS * 4);
    float* gcnt  = (float*)alloc(N_GRAPHS * 4);
    (void)ws_size; (void)n_in; (void)out_size;

    hipMemsetAsync(degs, 0, (size_t)N * 4, stream);
    hipMemsetAsync(degd, 0, (size_t)N * 4, stream);
    hipMemsetAsync(gsum, 0, N_GRAPHS * 4, stream);
    hipMemsetAsync(gcnt, 0, N_GRAPHS * 4, stream);

    k_degrees<<<(E + 255) / 256, 256, 0, stream>>>(src, dst, degs, degd, E);
    k_dinv<<<(N + 255) / 256, 256, 0, stream>>>(degs, degd, dsrc, ddst, N);
    k_fold_w<<<1, 128, 0, stream>>>(W3, b3, Wout, bout, wfold, cval);

    // CSR by dst
    const int nscan = (N + 1023) / 1024;   // 98 for N=100000 (<=256 required)
    k_scanA<<<nscan, 256, 0, stream>>>(degd, off, partials, N);
    k_scanB<<<1, 256, 0, stream>>>(partials, nscan);
    k_scanC<<<nscan, 256, 0, stream>>>(off, cursor, partials, N, E);
    k_csrfill<<<(E + 255) / 256, 256, 0, stream>>>(src, dst, cursor, csr, E);

    const int gblocks = (N + 31) / 32;
    const int agblocks = (N + 7) / 8;   // 8 nodes per 256-thread block

    // layer 1: T1 = (in_feat * dsrc) @ W1 -> P ; A1 = gather(T1) -> Q
    k_gemm128<0><<<gblocks, 256, 0, stream>>>(in_feat, P, W1, nullptr, nullptr, dsrc, N);
    k_gather128<<<agblocks, 256, 0, stream>>>(P, Q, csr, off, N);

    // layer 2: T2 = (lrelu(A1*ddst + b1) * dsrc) @ W2 (in place) ; A2 -> P
    k_gemm128<1><<<gblocks, 256, 0, stream>>>(Q, Q, W2, b1, ddst, dsrc, N);
    k_gather128<<<agblocks, 256, 0, stream>>>(Q, P, csr, off, N);

    // layer 3 (conv2 again): T3 = (lrelu(A2*ddst + b2) * dsrc) @ W2 (in place) ; A3 -> Q
    k_gemm128<1><<<gblocks, 256, 0, stream>>>(P, P, W2, b2, ddst, dsrc, N);
    k_gather128<<<agblocks, 256, 0, stream>>>(P, Q, csr, off, N);

    // folded conv3 + readout
    k_node_scalar<<<(N + 3) / 4, 256, 0, stream>>>(Q, ddst, dsrc, b2, wfold, tv, N);
    k_gather_final<<<(N + 255) / 256, 256, 0, stream>>>(tv, csr, off, ddst, gid, cval, gsum, gcnt, N);
    k_final<<<1, 128, 0, stream>>>(gsum, gcnt, out);
}

// Round 3
// 760.757 us; speedup vs baseline: 11.3610x; 1.2394x over previous
//
#include <hip/hip_runtime.h>
#include <math.h>

#define N_GRAPHS 100
#define HCHUNK 32768
#define HBLK 64

__device__ __forceinline__ float lrelu(float v) { return v >= 0.f ? v : 0.1f * v; }

// ---------------- chunked LDS histogram: per-block counts to scratch ----------------
// grid = nchunks * HBLK blocks of 512 threads; block (c,b) counts keys in
// [c*HCHUNK, (c+1)*HCHUNK) over its edge slice {b*512+t + m*HBLK*512}
__global__ __launch_bounds__(512, 1)
void k_hist(const int* __restrict__ keys, int* __restrict__ scratch, int E) {
    __shared__ int h[HCHUNK];   // 128 KiB
    const int c = blockIdx.x / HBLK;
    const int b = blockIdx.x % HBLK;
    const int base = c * HCHUNK;
    for (int i = threadIdx.x; i < HCHUNK; i += 512) h[i] = 0;
    __syncthreads();
    for (int i = b * 512 + threadIdx.x; i < E; i += HBLK * 512) {
        unsigned k = (unsigned)(keys[i] - base);
        if (k < HCHUNK) atomicAdd(&h[k], 1);
    }
    __syncthreads();
    int* outp = scratch + (size_t)blockIdx.x * HCHUNK;
    for (int i = threadIdx.x; i < HCHUNK; i += 512) outp[i] = h[i];
}

// reduce per-block counts -> degree; write dinv (and optionally int degree)
template <int WRITE_INT>
__global__ void k_hist_reduce(const int* __restrict__ scratch, int* __restrict__ deg_out,
                              float* __restrict__ dinv_out, int N) {
    int g = blockIdx.x * blockDim.x + threadIdx.x;
    if (g >= N) return;
    const int c = g >> 15;
    const int p = g & (HCHUNK - 1);
    const int* col = scratch + ((size_t)(c * HBLK)) * HCHUNK + p;
    int s = 0;
#pragma unroll 8
    for (int b = 0; b < HBLK; ++b) s += col[(size_t)b * HCHUNK];
    if (WRITE_INT) deg_out[g] = s;
    dinv_out[g] = rsqrtf(fmaxf((float)s, 1.0f));
}

// ---------------- fold W3 @ Wout -> w[128], c = b3.Wout + bout ----------------
__global__ void k_fold_w(const float* __restrict__ W3, const float* __restrict__ b3,
                         const float* __restrict__ Wout, const float* __restrict__ bout,
                         float* __restrict__ w, float* __restrict__ cval) {
    int i = threadIdx.x; // 128 threads
    float s = 0.f;
    for (int j = 0; j < 64; ++j) s += W3[i * 64 + j] * Wout[j];
    w[i] = s;
    if (i == 0) {
        float c = bout[0];
        for (int j = 0; j < 64; ++j) c += b3[j] * Wout[j];
        *cval = c;
    }
}

// ---------------- exclusive scan over degd -> off (3-kernel) ----------------
__global__ void k_scanA(const int* __restrict__ deg, int* __restrict__ off,
                        int* __restrict__ partials, int N) {
    __shared__ int ts[256];
    const int t = threadIdx.x;
    const int base = blockIdx.x * 1024 + t * 4;
    int v0 = (base + 0 < N) ? deg[base + 0] : 0;
    int v1 = (base + 1 < N) ? deg[base + 1] : 0;
    int v2 = (base + 2 < N) ? deg[base + 2] : 0;
    int v3 = (base + 3 < N) ? deg[base + 3] : 0;
    int s = v0 + v1 + v2 + v3;
    ts[t] = s;
    __syncthreads();
    for (int o = 1; o < 256; o <<= 1) {
        int y = (t >= o) ? ts[t - o] : 0;
        __syncthreads();
        ts[t] += y;
        __syncthreads();
    }
    int excl = ts[t] - s;
    if (base + 0 < N) off[base + 0] = excl;
    if (base + 1 < N) off[base + 1] = excl + v0;
    if (base + 2 < N) off[base + 2] = excl + v0 + v1;
    if (base + 3 < N) off[base + 3] = excl + v0 + v1 + v2;
    if (t == 255) partials[blockIdx.x] = ts[255];
}

__global__ void k_scanB(int* __restrict__ partials, int nb) {
    __shared__ int ps[256];
    const int t = threadIdx.x;
    int v = (t < nb) ? partials[t] : 0;
    ps[t] = v;
    __syncthreads();
    for (int o = 1; o < 256; o <<= 1) {
        int y = (t >= o) ? ps[t - o] : 0;
        __syncthreads();
        ps[t] += y;
        __syncthreads();
    }
    if (t < nb) partials[t] = ps[t] - v;
}

__global__ void k_scanC(int* __restrict__ off, const int* __restrict__ partials, int N, int E) {
    const int t = threadIdx.x;
    const int base = blockIdx.x * 1024 + t * 4;
    const int add = partials[blockIdx.x];
#pragma unroll
    for (int q = 0; q < 4; ++q) {
        int idx = base + q;
        if (idx < N) off[idx] += add;
    }
    if (blockIdx.x == 0 && t == 0) off[N] = E;
}

// ---------------- column-scan per-block counts -> per-block cursors ----------------
// scratch[c][b][p] := off[g] + sum_{b'<b} cnt[c][b'][p]
__global__ void k_colscan(int* __restrict__ scratch, const int* __restrict__ off,
                          int NBINS, int N) {
    int g = blockIdx.x * blockDim.x + threadIdx.x;
    if (g >= NBINS) return;
    const int c = g >> 15;
    const int p = g & (HCHUNK - 1);
    int* col = scratch + ((size_t)(c * HBLK)) * HCHUNK + p;
    int run = (g < N) ? off[g] : 0;
    for (int b = 0; b < HBLK; ++b) {
        int* q = col + (size_t)b * HCHUNK;
        int t = *q;
        *q = run;
        run += t;
    }
}

// ---------------- atomic-free(global) CSR fill via LDS cursors ----------------
__global__ __launch_bounds__(512, 1)
void k_csrfill2(const int* __restrict__ src, const int* __restrict__ dst,
                const int* __restrict__ scratch, int* __restrict__ csr, int E) {
    __shared__ int cur[HCHUNK];   // 128 KiB
    const int c = blockIdx.x / HBLK;
    const int b = blockIdx.x % HBLK;
    const int base = c * HCHUNK;
    const int* my = scratch + (size_t)(c * HBLK + b) * HCHUNK;
    for (int i = threadIdx.x; i < HCHUNK; i += 512) cur[i] = my[i];
    __syncthreads();
    for (int i = b * 512 + threadIdx.x; i < E; i += HBLK * 512) {
        unsigned k = (unsigned)(dst[i] - base);
        if (k < HCHUNK) {
            int p = atomicAdd(&cur[k], 1);
            csr[p] = src[i];
        }
    }
}

// ---------------- fused pre-norm + GEMM (in-place safe) ----------------
// PRE==0:  Y[r] = (X[r] * dinv_src[r]) @ W
// PRE==1:  Y[r] = (lrelu(X[r]*dinv_dst[r] + bias) * dinv_src[r]) @ W
// 128 rows/block, 512 threads, thread tile 4 rows x 8 cols. Xs/Ws XOR-swizzled.
template <int PRE>
__global__ __launch_bounds__(512, 1)
void k_gemm128(const float* __restrict__ X, float* __restrict__ Y,
               const float* __restrict__ W, const float* __restrict__ bias,
               const float* __restrict__ dinv_dst, const float* __restrict__ dinv_src,
               int N) {
    __shared__ float Ws[128 * 128];   // 64 KiB, col-segment swizzle
    __shared__ float Xs[128 * 128];   // 64 KiB, row-octet swizzle
    const int t = threadIdx.x;
    const int r0 = blockIdx.x * 128;

    for (int i = t; i < 4096; i += 512) {
        int k = i >> 5;
        int c4 = (i & 31) << 2;
        float4 v = ((const float4*)W)[i];
        int swc = ((c4 >> 5) & 3) << 2;
        *(float4*)&Ws[k * 128 + (c4 ^ swc)] = v;
    }
    for (int i = t; i < 4096; i += 512) {
        int r = i >> 5;
        int c4 = (i & 31) << 2;
        int row = r0 + r;
        float4 v = make_float4(0.f, 0.f, 0.f, 0.f);
        if (row < N) {
            v = ((const float4*)(X + (size_t)row * 128))[i & 31];
            float ds = dinv_src[row];
            if (PRE) {
                float dd = dinv_dst[row];
                v.x = lrelu(v.x * dd + bias[c4 + 0]) * ds;
                v.y = lrelu(v.y * dd + bias[c4 + 1]) * ds;
                v.z = lrelu(v.z * dd + bias[c4 + 2]) * ds;
                v.w = lrelu(v.w * dd + bias[c4 + 3]) * ds;
            } else {
                v.x *= ds; v.y *= ds; v.z *= ds; v.w *= ds;
            }
        }
        int swr = ((r >> 3) & 7) << 2;
        *(float4*)&Xs[r * 128 + (c4 ^ swr)] = v;
    }
    __syncthreads();

    const int rg = t >> 4;            // 0..31 -> rows 4rg..4rg+3
    const int cg = t & 15;            // cols 8cg..8cg+7
    const int swr = ((rg >> 1) & 7) << 2;           // row-octet swizzle (same for all 4 rows)
    const int cbase = 8 * cg;
    const int swc = ((cbase >> 5) & 3) << 2;
    const int q0 = cbase ^ swc;       // cols cbase..cbase+3 live here
    const int q1 = q0 ^ 4;            // cols cbase+4..cbase+7 live here

    float acc[4][8];
#pragma unroll
    for (int i = 0; i < 4; ++i)
#pragma unroll
        for (int j = 0; j < 8; ++j) acc[i][j] = 0.f;

#pragma unroll 8
    for (int k = 0; k < 128; ++k) {
        const int kx = k ^ swr;
        float x0 = Xs[(4 * rg + 0) * 128 + kx];
        float x1 = Xs[(4 * rg + 1) * 128 + kx];
        float x2 = Xs[(4 * rg + 2) * 128 + kx];
        float x3 = Xs[(4 * rg + 3) * 128 + kx];
        const float4 w0 = *(const float4*)&Ws[k * 128 + q0];
        const float4 w1 = *(const float4*)&Ws[k * 128 + q1];
        acc[0][0] += x0 * w0.x; acc[0][1] += x0 * w0.y; acc[0][2] += x0 * w0.z; acc[0][3] += x0 * w0.w;
        acc[0][4] += x0 * w1.x; acc[0][5] += x0 * w1.y; acc[0][6] += x0 * w1.z; acc[0][7] += x0 * w1.w;
        acc[1][0] += x1 * w0.x; acc[1][1] += x1 * w0.y; acc[1][2] += x1 * w0.z; acc[1][3] += x1 * w0.w;
        acc[1][4] += x1 * w1.x; acc[1][5] += x1 * w1.y; acc[1][6] += x1 * w1.z; acc[1][7] += x1 * w1.w;
        acc[2][0] += x2 * w0.x; acc[2][1] += x2 * w0.y; acc[2][2] += x2 * w0.z; acc[2][3] += x2 * w0.w;
        acc[2][4] += x2 * w1.x; acc[2][5] += x2 * w1.y; acc[2][6] += x2 * w1.z; acc[2][7] += x2 * w1.w;
        acc[3][0] += x3 * w0.x; acc[3][1] += x3 * w0.y; acc[3][2] += x3 * w0.z; acc[3][3] += x3 * w0.w;
        acc[3][4] += x3 * w1.x; acc[3][5] += x3 * w1.y; acc[3][6] += x3 * w1.z; acc[3][7] += x3 * w1.w;
    }

#pragma unroll
    for (int i = 0; i < 4; ++i) {
        int row = r0 + 4 * rg + i;
        if (row < N) {
            *(float4*)(Y + (size_t)row * 128 + cbase)     = make_float4(acc[i][0], acc[i][1], acc[i][2], acc[i][3]);
            *(float4*)(Y + (size_t)row * 128 + cbase + 4) = make_float4(acc[i][4], acc[i][5], acc[i][6], acc[i][7]);
        }
    }
}

// ---------------- CSR gather-aggregate: Y[n] = sum_{e: dst=n} T[src[e]] ----------------
__global__ __launch_bounds__(256)
void k_gather128(const float* __restrict__ T, float* __restrict__ Y,
                 const int* __restrict__ csr, const int* __restrict__ off, int N) {
    int n = blockIdx.x * 8 + (threadIdx.x >> 5);
    if (n >= N) return;
    const int lane = threadIdx.x & 31;
    const int c = lane << 2;
    int j = off[n];
    const int jend = off[n + 1];
    float4 a0 = make_float4(0.f, 0.f, 0.f, 0.f);
    float4 a1 = make_float4(0.f, 0.f, 0.f, 0.f);
    for (; j + 4 <= jend; j += 4) {
        int i0 = csr[j], i1 = csr[j + 1], i2 = csr[j + 2], i3 = csr[j + 3];
        float4 v0 = *(const float4*)(T + (size_t)i0 * 128 + c);
        float4 v1 = *(const float4*)(T + (size_t)i1 * 128 + c);
        float4 v2 = *(const float4*)(T + (size_t)i2 * 128 + c);
        float4 v3 = *(const float4*)(T + (size_t)i3 * 128 + c);
        a0.x += v0.x + v1.x; a0.y += v0.y + v1.y; a0.z += v0.z + v1.z; a0.w += v0.w + v1.w;
        a1.x += v2.x + v3.x; a1.y += v2.y + v3.y; a1.z += v2.z + v3.z; a1.w += v2.w + v3.w;
    }
    for (; j < jend; ++j) {
        int i0 = csr[j];
        float4 v0 = *(const float4*)(T + (size_t)i0 * 128 + c);
        a0.x += v0.x; a0.y += v0.y; a0.z += v0.z; a0.w += v0.w;
    }
    float4 r = make_float4(a0.x + a1.x, a0.y + a1.y, a0.z + a1.z, a0.w + a1.w);
    *(float4*)(Y + (size_t)n * 128 + c) = r;
}

// ---------------- folded conv3+readout: tv[n] = dinv_src[n]*(lrelu(A[n]*ddst+b2) . w) ----------------
__global__ void k_node_scalar(const float* __restrict__ A, const float* __restrict__ dinv_dst,
                              const float* __restrict__ dinv_src, const float* __restrict__ bias,
                              const float* __restrict__ w, float* __restrict__ tv, int N) {
    int gtid = blockIdx.x * blockDim.x + threadIdx.x;
    int wid = gtid >> 6;
    int lane = gtid & 63;
    if (wid >= N) return;
    float dd = dinv_dst[wid];
    const float* row = A + (size_t)wid * 128;
    float h0 = lrelu(row[lane] * dd + bias[lane]);
    float h1 = lrelu(row[lane + 64] * dd + bias[lane + 64]);
    float s = h0 * w[lane] + h1 * w[lane + 64];
#pragma unroll
    for (int o = 32; o > 0; o >>= 1) s += __shfl_down(s, o);
    if (lane == 0) tv[wid] = s * dinv_src[wid];
}

// ---------------- final: z[n]=sum tv[csr], s=z*ddst+c, per-graph mean bins ----------------
__global__ void k_gather_final(const float* __restrict__ tv, const int* __restrict__ csr,
                               const int* __restrict__ off, const float* __restrict__ ddst,
                               const int* __restrict__ gid, const float* __restrict__ cval,
                               float* __restrict__ gsum, float* __restrict__ gcnt, int N) {
    __shared__ float sb[N_GRAPHS], sc[N_GRAPHS];
    for (int i = threadIdx.x; i < N_GRAPHS; i += blockDim.x) { sb[i] = 0.f; sc[i] = 0.f; }
    __syncthreads();
    int n = blockIdx.x * blockDim.x + threadIdx.x;
    if (n < N) {
        int j = off[n], jend = off[n + 1];
        float z = 0.f;
        for (; j < jend; ++j) z += tv[csr[j]];
        float s = z * ddst[n] + cval[0];
        int g = gid[n];
        atomicAdd(&sb[g], s);
        atomicAdd(&sc[g], 1.f);
    }
    __syncthreads();
    for (int j = threadIdx.x; j < N_GRAPHS; j += blockDim.x) {
        if (sc[j] != 0.f) {
            atomicAdd(&gsum[j], sb[j]);
            atomicAdd(&gcnt[j], sc[j]);
        }
    }
}

__global__ void k_final(const float* __restrict__ gsum, const float* __restrict__ gcnt,
                        float* __restrict__ out) {
    int g = threadIdx.x;
    if (g < N_GRAPHS) out[g] = gsum[g] / fmaxf(gcnt[g], 1.0f);
}

extern "C" void kernel_launch(void* const* d_in, const int* in_sizes, int n_in,
                              void* d_out, int out_size, void* d_ws, size_t ws_size,
                              hipStream_t stream) {
    const float* in_feat = (const float*)d_in[0];
    const float* W1   = (const float*)d_in[1];
    const float* b1   = (const float*)d_in[2];
    const float* W2   = (const float*)d_in[3];
    const float* b2   = (const float*)d_in[4];
    const float* W3   = (const float*)d_in[5];
    const float* b3   = (const float*)d_in[6];
    const float* Wout = (const float*)d_in[7];
    const float* bout = (const float*)d_in[8];
    const int* src = (const int*)d_in[9];
    const int* dst = (const int*)d_in[10];
    const int* gid = (const int*)d_in[11];
    const int N = in_sizes[0] / 128;
    const int E = in_sizes[9];
    float* out = (float*)d_out;

    char* ws = (char*)d_ws;
    size_t woff = 0;
    auto alloc = [&](size_t bytes) {
        void* p = ws + woff;
        woff = (woff + bytes + 255) & ~(size_t)255;
        return p;
    };
    float* P     = (float*)alloc((size_t)N * 128 * 4);
    float* Q     = (float*)alloc((size_t)N * 128 * 4);
    int*   csr   = (int*)alloc((size_t)E * 4);
    int*   degd  = (int*)alloc((size_t)N * 4);
    int*   off   = (int*)alloc((size_t)(N + 1) * 4);
    int*   partials = (int*)alloc(256 * 4);
    float* dsrc  = (float*)alloc((size_t)N * 4);
    float* ddst  = (float*)alloc((size_t)N * 4);
    float* tv    = (float*)alloc((size_t)N * 4);
    float* wfold = (float*)alloc(128 * 4);
    float* cval  = (float*)alloc(4);
    float* gsum  = (float*)alloc(N_GRAPHS * 4);
    float* gcnt  = (float*)alloc(N_GRAPHS * 4);
    (void)ws_size; (void)n_in; (void)out_size;

    const int nchunks = (N + HCHUNK - 1) / HCHUNK;         // 4 for N=100000
    const int NBINS = nchunks * HCHUNK;
    // histogram scratch aliases P (P is first written by layer-1 GEMM, after CSR build)
    int* scratch = (int*)P;   // nchunks*HBLK*HCHUNK*4 = 33.5 MB < 51.2 MB

    hipMemsetAsync(gsum, 0, N_GRAPHS * 4, stream);
    hipMemsetAsync(gcnt, 0, N_GRAPHS * 4, stream);

    k_fold_w<<<1, 128, 0, stream>>>(W3, b3, Wout, bout, wfold, cval);

    // degrees via chunked LDS histograms (no global atomics)
    k_hist<<<nchunks * HBLK, 512, 0, stream>>>(src, scratch, E);
    k_hist_reduce<0><<<(N + 255) / 256, 256, 0, stream>>>(scratch, nullptr, dsrc, N);
    k_hist<<<nchunks * HBLK, 512, 0, stream>>>(dst, scratch, E);
    k_hist_reduce<1><<<(N + 255) / 256, 256, 0, stream>>>(scratch, degd, ddst, N);

    // CSR offsets
    const int nscan = (N + 1023) / 1024;   // 98 (<=256 required)
    k_scanA<<<nscan, 256, 0, stream>>>(degd, off, partials, N);
    k_scanB<<<1, 256, 0, stream>>>(partials, nscan);
    k_scanC<<<nscan, 256, 0, stream>>>(off, partials, N, E);

    // per-block cursors, then counting-sort fill (LDS atomics only)
    k_colscan<<<(NBINS + 255) / 256, 256, 0, stream>>>(scratch, off, NBINS, N);
    k_csrfill2<<<nchunks * HBLK, 512, 0, stream>>>(src, dst, scratch, csr, E);

    const int gblocks = (N + 127) / 128;
    const int agblocks = (N + 7) / 8;

    // layer 1: T1 = (in_feat * dsrc) @ W1 -> P ; A1 = gather(T1) -> Q
    k_gemm128<0><<<gblocks, 512, 0, stream>>>(in_feat, P, W1, nullptr, nullptr, dsrc, N);
    k_gather128<<<agblocks, 256, 0, stream>>>(P, Q, csr, off, N);

    // layer 2: T2 = (lrelu(A1*ddst + b1) * dsrc) @ W2 (in place) ; A2 -> P
    k_gemm128<1><<<gblocks, 512, 0, stream>>>(Q, Q, W2, b1, ddst, dsrc, N);
    k_gather128<<<agblocks, 256, 0, stream>>>(Q, P, csr, off, N);

    // layer 3 (conv2 again): T3 = (lrelu(A2*ddst + b2) * dsrc) @ W2 (in place) ; A3 -> Q
    k_gemm128<1><<<gblocks, 512, 0, stream>>>(P, P, W2, b2, ddst, dsrc, N);
    k_gather128<<<agblocks, 256, 0, stream>>>(P, Q, csr, off, N);

    // folded conv3 + readout
    k_node_scalar<<<(N + 3) / 4, 256, 0, stream>>>(Q, ddst, dsrc, b2, wfold, tv, N);
    k_gather_final<<<(N + 255) / 256, 256, 0, stream>>>(tv, csr, off, ddst, gid, cval, gsum, gcnt, N);
    k_final<<<1, 128, 0, stream>>>(gsum, gcnt, out);
}

// Round 4
// 669.398 us; speedup vs baseline: 12.9116x; 1.1365x over previous
//
#include <hip/hip_runtime.h>
#include <math.h>

#define N_GRAPHS 100
#define HCHUNK 32768
#define HBLK 64

typedef __attribute__((ext_vector_type(8))) short bf16x8;
typedef __attribute__((ext_vector_type(4))) float f32x4;

__device__ __forceinline__ float lrelu(float v) { return v >= 0.f ? v : 0.1f * v; }

__device__ __forceinline__ unsigned short f2bf(float x) {
    unsigned u = __float_as_uint(x);
    unsigned r = u + 0x7FFF + ((u >> 16) & 1);
    return (unsigned short)(r >> 16);
}
__device__ __forceinline__ float bf2f(unsigned short h) {
    return __uint_as_float(((unsigned)h) << 16);
}

// ---------------- chunked LDS histogram: per-block counts to scratch ----------------
__global__ __launch_bounds__(512, 1)
void k_hist(const int* __restrict__ keys, int* __restrict__ scratch, int E) {
    __shared__ int h[HCHUNK];   // 128 KiB
    const int c = blockIdx.x / HBLK;
    const int b = blockIdx.x % HBLK;
    const int base = c * HCHUNK;
    for (int i = threadIdx.x; i < HCHUNK; i += 512) h[i] = 0;
    __syncthreads();
    for (int i = b * 512 + threadIdx.x; i < E; i += HBLK * 512) {
        unsigned k = (unsigned)(keys[i] - base);
        if (k < HCHUNK) atomicAdd(&h[k], 1);
    }
    __syncthreads();
    int* outp = scratch + (size_t)blockIdx.x * HCHUNK;
    for (int i = threadIdx.x; i < HCHUNK; i += 512) outp[i] = h[i];
}

template <int WRITE_INT>
__global__ void k_hist_reduce(const int* __restrict__ scratch, int* __restrict__ deg_out,
                              float* __restrict__ dinv_out, int N) {
    int g = blockIdx.x * blockDim.x + threadIdx.x;
    if (g >= N) return;
    const int c = g >> 15;
    const int p = g & (HCHUNK - 1);
    const int* col = scratch + ((size_t)(c * HBLK)) * HCHUNK + p;
    int s = 0;
#pragma unroll 8
    for (int b = 0; b < HBLK; ++b) s += col[(size_t)b * HCHUNK];
    if (WRITE_INT) deg_out[g] = s;
    dinv_out[g] = rsqrtf(fmaxf((float)s, 1.0f));
}

// ---------------- fold W3 @ Wout -> w[128], c = b3.Wout + bout ----------------
__global__ void k_fold_w(const float* __restrict__ W3, const float* __restrict__ b3,
                         const float* __restrict__ Wout, const float* __restrict__ bout,
                         float* __restrict__ w, float* __restrict__ cval) {
    int i = threadIdx.x; // 128 threads
    float s = 0.f;
    for (int j = 0; j < 64; ++j) s += W3[i * 64 + j] * Wout[j];
    w[i] = s;
    if (i == 0) {
        float c = bout[0];
        for (int j = 0; j < 64; ++j) c += b3[j] * Wout[j];
        *cval = c;
    }
}

// ---------------- split W (128x128 fp32) -> transposed+swizzled bf16 hi/lo ----------------
// whi[col*128 + (k ^ ((col&31)<<2))] = hi(W[k][col]) ; same for lo
__global__ void k_wsplit(const float* __restrict__ W, unsigned short* __restrict__ whi,
                         unsigned short* __restrict__ wlo) {
    int t = threadIdx.x;
    for (int i = t; i < 16384; i += 256) {
        int k = i >> 7, col = i & 127;
        float x = W[i];
        unsigned short h = f2bf(x);
        unsigned short l = f2bf(x - bf2f(h));
        int dsti = col * 128 + (k ^ ((col & 31) << 2));
        whi[dsti] = h;
        wlo[dsti] = l;
    }
}

// ---------------- exclusive scan over degd -> off (3-kernel) ----------------
__global__ void k_scanA(const int* __restrict__ deg, int* __restrict__ off,
                        int* __restrict__ partials, int N) {
    __shared__ int ts[256];
    const int t = threadIdx.x;
    const int base = blockIdx.x * 1024 + t * 4;
    int v0 = (base + 0 < N) ? deg[base + 0] : 0;
    int v1 = (base + 1 < N) ? deg[base + 1] : 0;
    int v2 = (base + 2 < N) ? deg[base + 2] : 0;
    int v3 = (base + 3 < N) ? deg[base + 3] : 0;
    int s = v0 + v1 + v2 + v3;
    ts[t] = s;
    __syncthreads();
    for (int o = 1; o < 256; o <<= 1) {
        int y = (t >= o) ? ts[t - o] : 0;
        __syncthreads();
        ts[t] += y;
        __syncthreads();
    }
    int excl = ts[t] - s;
    if (base + 0 < N) off[base + 0] = excl;
    if (base + 1 < N) off[base + 1] = excl + v0;
    if (base + 2 < N) off[base + 2] = excl + v0 + v1;
    if (base + 3 < N) off[base + 3] = excl + v0 + v1 + v2;
    if (t == 255) partials[blockIdx.x] = ts[255];
}

__global__ void k_scanB(int* __restrict__ partials, int nb) {
    __shared__ int ps[256];
    const int t = threadIdx.x;
    int v = (t < nb) ? partials[t] : 0;
    ps[t] = v;
    __syncthreads();
    for (int o = 1; o < 256; o <<= 1) {
        int y = (t >= o) ? ps[t - o] : 0;
        __syncthreads();
        ps[t] += y;
        __syncthreads();
    }
    if (t < nb) partials[t] = ps[t] - v;
}

__global__ void k_scanC(int* __restrict__ off, const int* __restrict__ partials, int N, int E) {
    const int t = threadIdx.x;
    const int base = blockIdx.x * 1024 + t * 4;
    const int add = partials[blockIdx.x];
#pragma unroll
    for (int q = 0; q < 4; ++q) {
        int idx = base + q;
        if (idx < N) off[idx] += add;
    }
    if (blockIdx.x == 0 && t == 0) off[N] = E;
}

// ---------------- column-scan per-block counts -> per-block cursors ----------------
__global__ void k_colscan(int* __restrict__ scratch, const int* __restrict__ off,
                          int NBINS, int N) {
    int g = blockIdx.x * blockDim.x + threadIdx.x;
    if (g >= NBINS) return;
    const int c = g >> 15;
    const int p = g & (HCHUNK - 1);
    int* col = scratch + ((size_t)(c * HBLK)) * HCHUNK + p;
    int run = (g < N) ? off[g] : 0;
    for (int b = 0; b < HBLK; ++b) {
        int* q = col + (size_t)b * HCHUNK;
        int t = *q;
        *q = run;
        run += t;
    }
}

// ---------------- atomic-free(global) CSR fill via LDS cursors ----------------
__global__ __launch_bounds__(512, 1)
void k_csrfill2(const int* __restrict__ src, const int* __restrict__ dst,
                const int* __restrict__ scratch, int* __restrict__ csr, int E) {
    __shared__ int cur[HCHUNK];   // 128 KiB
    const int c = blockIdx.x / HBLK;
    const int b = blockIdx.x % HBLK;
    const int base = c * HCHUNK;
    const int* my = scratch + (size_t)(c * HBLK + b) * HCHUNK;
    for (int i = threadIdx.x; i < HCHUNK; i += 512) cur[i] = my[i];
    __syncthreads();
    for (int i = b * 512 + threadIdx.x; i < E; i += HBLK * 512) {
        unsigned k = (unsigned)(dst[i] - base);
        if (k < HCHUNK) {
            int p = atomicAdd(&cur[k], 1);
            csr[p] = src[i];
        }
    }
}

// ---------------- MFMA split-bf16 GEMM:  Y = pre(X) @ W  (in-place safe) ----------------
// pre: PRE==0: x*dinv_src ; PRE==1: lrelu(x*dinv_dst + bias)*dinv_src
// X split per-block into LDS bf16 hi/lo (XOR-swizzled); W pre-split global (k_wsplit).
// Block: 512 thr (8 waves), 128 rows x 128 cols. Wave (wm=w&3, wn=w>>2):
//   rows 32*wm..+31 (2 M-frags), cols 64*wn..+63 (4 N-frags).
// mfma_f32_16x16x32_bf16: A lane l elem j: row=l&15, k=4*(l>>4)+(j&3)+16*(j>>2)
//                         B lane l elem j: col=l&15, k same ; D: row=(l>>4)*4+r, col=l&15
template <int PRE>
__global__ __launch_bounds__(512, 1)
void k_gemm_mfma(const float* __restrict__ X, float* __restrict__ Y,
                 const unsigned short* __restrict__ whiT, const unsigned short* __restrict__ wloT,
                 const float* __restrict__ bias, const float* __restrict__ dinv_dst,
                 const float* __restrict__ dinv_src, int N) {
    __shared__ unsigned short Xhi[128 * 128];  // 32 KiB each
    __shared__ unsigned short Xlo[128 * 128];
    __shared__ unsigned short Whi[128 * 128];  // transposed+swizzled: [col][k^((col&31)<<2)]
    __shared__ unsigned short Wlo[128 * 128];
    const int t = threadIdx.x;
    const int r0 = blockIdx.x * 128;

    for (int i = t; i < 2048; i += 512) ((float4*)Whi)[i] = ((const float4*)whiT)[i];
    for (int i = t; i < 2048; i += 512) ((float4*)Wlo)[i] = ((const float4*)wloT)[i];

    // stage + pre + split X: 4096 granules of 4 elems
    for (int i = t; i < 4096; i += 512) {
        int row = i >> 5;
        int g4 = (i & 31) << 2;
        int grow = r0 + row;
        float4 v = make_float4(0.f, 0.f, 0.f, 0.f);
        if (grow < N) {
            v = ((const float4*)(X + (size_t)grow * 128))[i & 31];
            float ds = dinv_src[grow];
            if (PRE) {
                float dd = dinv_dst[grow];
                v.x = lrelu(v.x * dd + bias[g4 + 0]) * ds;
                v.y = lrelu(v.y * dd + bias[g4 + 1]) * ds;
                v.z = lrelu(v.z * dd + bias[g4 + 2]) * ds;
                v.w = lrelu(v.w * dd + bias[g4 + 3]) * ds;
            } else {
                v.x *= ds; v.y *= ds; v.z *= ds; v.w *= ds;
            }
        }
        unsigned short h0 = f2bf(v.x), h1 = f2bf(v.y), h2 = f2bf(v.z), h3 = f2bf(v.w);
        unsigned short l0 = f2bf(v.x - bf2f(h0)), l1 = f2bf(v.y - bf2f(h1));
        unsigned short l2 = f2bf(v.z - bf2f(h2)), l3 = f2bf(v.w - bf2f(h3));
        int ks = row * 128 + (g4 ^ ((row & 31) << 2));
        Xhi[ks + 0] = h0; Xhi[ks + 1] = h1; Xhi[ks + 2] = h2; Xhi[ks + 3] = h3;
        Xlo[ks + 0] = l0; Xlo[ks + 1] = l1; Xlo[ks + 2] = l2; Xlo[ks + 3] = l3;
    }
    __syncthreads();

    const int w = t >> 6;
    const int wm = w & 3;          // row group: 32*wm
    const int wn = w >> 2;         // col group: 64*wn
    const int lane = t & 63;
    const int lr = lane & 15;
    const int lg = lane >> 4;

    f32x4 acc[2][4];
#pragma unroll
    for (int mi = 0; mi < 2; ++mi)
#pragma unroll
        for (int ni = 0; ni < 4; ++ni) acc[mi][ni] = (f32x4){0.f, 0.f, 0.f, 0.f};

#pragma unroll
    for (int ks = 0; ks < 4; ++ks) {
        const int k0 = 32 * ks + 4 * lg;
        // A frags
        bf16x8 ah[2], al[2];
#pragma unroll
        for (int mi = 0; mi < 2; ++mi) {
            int row = 32 * wm + 16 * mi + lr;
            int sw = (row & 31) << 2;
            int o1 = row * 128 + (k0 ^ sw);
            int o2 = row * 128 + ((k0 + 16) ^ sw);
            union { uint4 u; bf16x8 v; } uh, ul;
            uh.u.x = *(const unsigned*)&Xhi[o1];     uh.u.y = *(const unsigned*)&Xhi[o1 + 2];
            uh.u.z = *(const unsigned*)&Xhi[o2];     uh.u.w = *(const unsigned*)&Xhi[o2 + 2];
            ul.u.x = *(const unsigned*)&Xlo[o1];     ul.u.y = *(const unsigned*)&Xlo[o1 + 2];
            ul.u.z = *(const unsigned*)&Xlo[o2];     ul.u.w = *(const unsigned*)&Xlo[o2 + 2];
            ah[mi] = uh.v; al[mi] = ul.v;
        }
#pragma unroll
        for (int ni = 0; ni < 4; ++ni) {
            int colv = 64 * wn + 16 * ni + lr;
            int sw = (colv & 31) << 2;
            int o1 = colv * 128 + (k0 ^ sw);
            int o2 = colv * 128 + ((k0 + 16) ^ sw);
            union { uint4 u; bf16x8 v; } bh, bl;
            bh.u.x = *(const unsigned*)&Whi[o1];     bh.u.y = *(const unsigned*)&Whi[o1 + 2];
            bh.u.z = *(const unsigned*)&Whi[o2];     bh.u.w = *(const unsigned*)&Whi[o2 + 2];
            bl.u.x = *(const unsigned*)&Wlo[o1];     bl.u.y = *(const unsigned*)&Wlo[o1 + 2];
            bl.u.z = *(const unsigned*)&Wlo[o2];     bl.u.w = *(const unsigned*)&Wlo[o2 + 2];
#pragma unroll
            for (int mi = 0; mi < 2; ++mi) {
                acc[mi][ni] = __builtin_amdgcn_mfma_f32_16x16x32_bf16(ah[mi], bh.v, acc[mi][ni], 0, 0, 0);
                acc[mi][ni] = __builtin_amdgcn_mfma_f32_16x16x32_bf16(ah[mi], bl.v, acc[mi][ni], 0, 0, 0);
                acc[mi][ni] = __builtin_amdgcn_mfma_f32_16x16x32_bf16(al[mi], bh.v, acc[mi][ni], 0, 0, 0);
            }
        }
    }

    // epilogue: D row=(l>>4)*4+r (within frag), col=l&15
#pragma unroll
    for (int mi = 0; mi < 2; ++mi) {
#pragma unroll
        for (int r = 0; r < 4; ++r) {
            int row = r0 + 32 * wm + 16 * mi + 4 * lg + r;
            if (row < N) {
#pragma unroll
                for (int ni = 0; ni < 4; ++ni) {
                    Y[(size_t)row * 128 + 64 * wn + 16 * ni + lr] = acc[mi][ni][r];
                }
            }
        }
    }
}

// ---------------- CSR gather-aggregate: Y[n] = sum_{e: dst=n} T[src[e]] ----------------
__global__ __launch_bounds__(256)
void k_gather128(const float* __restrict__ T, float* __restrict__ Y,
                 const int* __restrict__ csr, const int* __restrict__ off, int N) {
    int n = blockIdx.x * 8 + (threadIdx.x >> 5);
    if (n >= N) return;
    const int lane = threadIdx.x & 31;
    const int c = lane << 2;
    int j = off[n];
    const int jend = off[n + 1];
    float4 a0 = make_float4(0.f, 0.f, 0.f, 0.f);
    float4 a1 = make_float4(0.f, 0.f, 0.f, 0.f);
    for (; j + 4 <= jend; j += 4) {
        int i0 = csr[j], i1 = csr[j + 1], i2 = csr[j + 2], i3 = csr[j + 3];
        float4 v0 = *(const float4*)(T + (size_t)i0 * 128 + c);
        float4 v1 = *(const float4*)(T + (size_t)i1 * 128 + c);
        float4 v2 = *(const float4*)(T + (size_t)i2 * 128 + c);
        float4 v3 = *(const float4*)(T + (size_t)i3 * 128 + c);
        a0.x += v0.x + v1.x; a0.y += v0.y + v1.y; a0.z += v0.z + v1.z; a0.w += v0.w + v1.w;
        a1.x += v2.x + v3.x; a1.y += v2.y + v3.y; a1.z += v2.z + v3.z; a1.w += v2.w + v3.w;
    }
    for (; j < jend; ++j) {
        int i0 = csr[j];
        float4 v0 = *(const float4*)(T + (size_t)i0 * 128 + c);
        a0.x += v0.x; a0.y += v0.y; a0.z += v0.z; a0.w += v0.w;
    }
    float4 r = make_float4(a0.x + a1.x, a0.y + a1.y, a0.z + a1.z, a0.w + a1.w);
    *(float4*)(Y + (size_t)n * 128 + c) = r;
}

// ---------------- folded conv3+readout ----------------
__global__ void k_node_scalar(const float* __restrict__ A, const float* __restrict__ dinv_dst,
                              const float* __restrict__ dinv_src, const float* __restrict__ bias,
                              const float* __restrict__ w, float* __restrict__ tv, int N) {
    int gtid = blockIdx.x * blockDim.x + threadIdx.x;
    int wid = gtid >> 6;
    int lane = gtid & 63;
    if (wid >= N) return;
    float dd = dinv_dst[wid];
    const float* row = A + (size_t)wid * 128;
    float h0 = lrelu(row[lane] * dd + bias[lane]);
    float h1 = lrelu(row[lane + 64] * dd + bias[lane + 64]);
    float s = h0 * w[lane] + h1 * w[lane + 64];
#pragma unroll
    for (int o = 32; o > 0; o >>= 1) s += __shfl_down(s, o);
    if (lane == 0) tv[wid] = s * dinv_src[wid];
}

// ---------------- final: z[n]=sum tv[csr], s=z*ddst+c, per-graph mean bins ----------------
__global__ void k_gather_final(const float* __restrict__ tv, const int* __restrict__ csr,
                               const int* __restrict__ off, const float* __restrict__ ddst,
                               const int* __restrict__ gid, const float* __restrict__ cval,
                               float* __restrict__ gsum, float* __restrict__ gcnt, int N) {
    __shared__ float sb[N_GRAPHS], sc[N_GRAPHS];
    for (int i = threadIdx.x; i < N_GRAPHS; i += blockDim.x) { sb[i] = 0.f; sc[i] = 0.f; }
    __syncthreads();
    int n = blockIdx.x * blockDim.x + threadIdx.x;
    if (n < N) {
        int j = off[n], jend = off[n + 1];
        float z = 0.f;
        for (; j < jend; ++j) z += tv[csr[j]];
        float s = z * ddst[n] + cval[0];
        int g = gid[n];
        atomicAdd(&sb[g], s);
        atomicAdd(&sc[g], 1.f);
    }
    __syncthreads();
    for (int j = threadIdx.x; j < N_GRAPHS; j += blockDim.x) {
        if (sc[j] != 0.f) {
            atomicAdd(&gsum[j], sb[j]);
            atomicAdd(&gcnt[j], sc[j]);
        }
    }
}

__global__ void k_final(const float* __restrict__ gsum, const float* __restrict__ gcnt,
                        float* __restrict__ out) {
    int g = threadIdx.x;
    if (g < N_GRAPHS) out[g] = gsum[g] / fmaxf(gcnt[g], 1.0f);
}

extern "C" void kernel_launch(void* const* d_in, const int* in_sizes, int n_in,
                              void* d_out, int out_size, void* d_ws, size_t ws_size,
                              hipStream_t stream) {
    const float* in_feat = (const float*)d_in[0];
    const float* W1   = (const float*)d_in[1];
    const float* b1   = (const float*)d_in[2];
    const float* W2   = (const float*)d_in[3];
    const float* b2   = (const float*)d_in[4];
    const float* W3   = (const float*)d_in[5];
    const float* b3   = (const float*)d_in[6];
    const float* Wout = (const float*)d_in[7];
    const float* bout = (const float*)d_in[8];
    const int* src = (const int*)d_in[9];
    const int* dst = (const int*)d_in[10];
    const int* gid = (const int*)d_in[11];
    const int N = in_sizes[0] / 128;
    const int E = in_sizes[9];
    float* out = (float*)d_out;

    char* ws = (char*)d_ws;
    size_t woff = 0;
    auto alloc = [&](size_t bytes) {
        void* p = ws + woff;
        woff = (woff + bytes + 255) & ~(size_t)255;
        return p;
    };
    float* P     = (float*)alloc((size_t)N * 128 * 4);
    float* Q     = (float*)alloc((size_t)N * 128 * 4);
    int*   csr   = (int*)alloc((size_t)E * 4);
    int*   degd  = (int*)alloc((size_t)N * 4);
    int*   off   = (int*)alloc((size_t)(N + 1) * 4);
    int*   partials = (int*)alloc(256 * 4);
    float* dsrc  = (float*)alloc((size_t)N * 4);
    float* ddst  = (float*)alloc((size_t)N * 4);
    float* tv    = (float*)alloc((size_t)N * 4);
    float* wfold = (float*)alloc(128 * 4);
    float* cval  = (float*)alloc(4);
    float* gsum  = (float*)alloc(N_GRAPHS * 4);
    float* gcnt  = (float*)alloc(N_GRAPHS * 4);
    unsigned short* w1hi = (unsigned short*)alloc(16384 * 2);
    unsigned short* w1lo = (unsigned short*)alloc(16384 * 2);
    unsigned short* w2hi = (unsigned short*)alloc(16384 * 2);
    unsigned short* w2lo = (unsigned short*)alloc(16384 * 2);
    (void)ws_size; (void)n_in; (void)out_size;

    const int nchunks = (N + HCHUNK - 1) / HCHUNK;         // 4 for N=100000
    const int NBINS = nchunks * HCHUNK;
    int* scratch = (int*)P;   // aliases P (first real write to P is layer-1 GEMM)

    hipMemsetAsync(gsum, 0, N_GRAPHS * 4, stream);
    hipMemsetAsync(gcnt, 0, N_GRAPHS * 4, stream);

    k_fold_w<<<1, 128, 0, stream>>>(W3, b3, Wout, bout, wfold, cval);
    k_wsplit<<<1, 256, 0, stream>>>(W1, w1hi, w1lo);
    k_wsplit<<<1, 256, 0, stream>>>(W2, w2hi, w2lo);

    // degrees via chunked LDS histograms (no global atomics)
    k_hist<<<nchunks * HBLK, 512, 0, stream>>>(src, scratch, E);
    k_hist_reduce<0><<<(N + 255) / 256, 256, 0, stream>>>(scratch, nullptr, dsrc, N);
    k_hist<<<nchunks * HBLK, 512, 0, stream>>>(dst, scratch, E);
    k_hist_reduce<1><<<(N + 255) / 256, 256, 0, stream>>>(scratch, degd, ddst, N);

    // CSR offsets
    const int nscan = (N + 1023) / 1024;
    k_scanA<<<nscan, 256, 0, stream>>>(degd, off, partials, N);
    k_scanB<<<1, 256, 0, stream>>>(partials, nscan);
    k_scanC<<<nscan, 256, 0, stream>>>(off, partials, N, E);

    // per-block cursors, then counting-sort fill (LDS atomics only)
    k_colscan<<<(NBINS + 255) / 256, 256, 0, stream>>>(scratch, off, NBINS, N);
    k_csrfill2<<<nchunks * HBLK, 512, 0, stream>>>(src, dst, scratch, csr, E);

    const int gblocks = (N + 127) / 128;
    const int agblocks = (N + 7) / 8;

    // layer 1: T1 = (in_feat * dsrc) @ W1 -> P ; A1 = gather(T1) -> Q
    k_gemm_mfma<0><<<gblocks, 512, 0, stream>>>(in_feat, P, w1hi, w1lo, nullptr, nullptr, dsrc, N);
    k_gather128<<<agblocks, 256, 0, stream>>>(P, Q, csr, off, N);

    // layer 2: T2 = (lrelu(A1*ddst + b1) * dsrc) @ W2 (in place) ; A2 -> P
    k_gemm_mfma<1><<<gblocks, 512, 0, stream>>>(Q, Q, w2hi, w2lo, b1, ddst, dsrc, N);
    k_gather128<<<agblocks, 256, 0, stream>>>(Q, P, csr, off, N);

    // layer 3 (conv2 again): T3 = (lrelu(A2*ddst + b2) * dsrc) @ W2 (in place) ; A3 -> Q
    k_gemm_mfma<1><<<gblocks, 512, 0, stream>>>(P, P, w2hi, w2lo, b2, ddst, dsrc, N);
    k_gather128<<<agblocks, 256, 0, stream>>>(P, Q, csr, off, N);

    // folded conv3 + readout
    k_node_scalar<<<(N + 3) / 4, 256, 0, stream>>>(Q, ddst, dsrc, b2, wfold, tv, N);
    k_gather_final<<<(N + 255) / 256, 256, 0, stream>>>(tv, csr, off, ddst, gid, cval, gsum, gcnt, N);
    k_final<<<1, 128, 0, stream>>>(gsum, gcnt, out);
}

// Round 5
// 503.136 us; speedup vs baseline: 17.1782x; 1.3305x over previous
//
#include <hip/hip_runtime.h>
#include <hip/hip_fp16.h>
#include <math.h>

#define N_GRAPHS 100
#define HCHUNK 32768
#define HBLK 64

typedef __attribute__((ext_vector_type(8))) short bf16x8;
typedef __attribute__((ext_vector_type(4))) float f32x4;

__device__ __forceinline__ float lrelu(float v) { return v >= 0.f ? v : 0.1f * v; }

__device__ __forceinline__ unsigned short f2bf(float x) {
    unsigned u = __float_as_uint(x);
    unsigned r = u + 0x7FFF + ((u >> 16) & 1);
    return (unsigned short)(r >> 16);
}
__device__ __forceinline__ float bf2f(unsigned short h) {
    return __uint_as_float(((unsigned)h) << 16);
}

// ---------------- chunked LDS histogram: per-block counts to scratch ----------------
__global__ __launch_bounds__(512, 1)
void k_hist(const int* __restrict__ keys, int* __restrict__ scratch, int E) {
    __shared__ int h[HCHUNK];   // 128 KiB
    const int c = blockIdx.x / HBLK;
    const int b = blockIdx.x % HBLK;
    const int base = c * HCHUNK;
    for (int i = threadIdx.x; i < HCHUNK; i += 512) h[i] = 0;
    __syncthreads();
    for (int i = b * 512 + threadIdx.x; i < E; i += HBLK * 512) {
        unsigned k = (unsigned)(keys[i] - base);
        if (k < HCHUNK) atomicAdd(&h[k], 1);
    }
    __syncthreads();
    int* outp = scratch + (size_t)blockIdx.x * HCHUNK;
    for (int i = threadIdx.x; i < HCHUNK; i += 512) outp[i] = h[i];
}

template <int WRITE_INT>
__global__ void k_hist_reduce(const int* __restrict__ scratch, int* __restrict__ deg_out,
                              float* __restrict__ dinv_out, int N) {
    int g = blockIdx.x * blockDim.x + threadIdx.x;
    if (g >= N) return;
    const int c = g >> 15;
    const int p = g & (HCHUNK - 1);
    const int* col = scratch + ((size_t)(c * HBLK)) * HCHUNK + p;
    int s = 0;
#pragma unroll 8
    for (int b = 0; b < HBLK; ++b) s += col[(size_t)b * HCHUNK];
    if (WRITE_INT) deg_out[g] = s;
    dinv_out[g] = rsqrtf(fmaxf((float)s, 1.0f));
}

// ---------------- fold W3 @ Wout -> w[128], c = b3.Wout + bout ----------------
__global__ void k_fold_w(const float* __restrict__ W3, const float* __restrict__ b3,
                         const float* __restrict__ Wout, const float* __restrict__ bout,
                         float* __restrict__ w, float* __restrict__ cval) {
    int i = threadIdx.x; // 128 threads
    float s = 0.f;
    for (int j = 0; j < 64; ++j) s += W3[i * 64 + j] * Wout[j];
    w[i] = s;
    if (i == 0) {
        float c = bout[0];
        for (int j = 0; j < 64; ++j) c += b3[j] * Wout[j];
        *cval = c;
    }
}

// ---------------- split W (128x128 fp32) -> transposed+swizzled bf16 hi/lo ----------------
__global__ void k_wsplit(const float* __restrict__ W, unsigned short* __restrict__ whi,
                         unsigned short* __restrict__ wlo) {
    int t = threadIdx.x;
    for (int i = t; i < 16384; i += 256) {
        int k = i >> 7, col = i & 127;
        float x = W[i];
        unsigned short h = f2bf(x);
        unsigned short l = f2bf(x - bf2f(h));
        int dsti = col * 128 + (k ^ ((col & 31) << 2));
        whi[dsti] = h;
        wlo[dsti] = l;
    }
}

// ---------------- exclusive scan over degd -> off (3-kernel) ----------------
__global__ void k_scanA(const int* __restrict__ deg, int* __restrict__ off,
                        int* __restrict__ partials, int N) {
    __shared__ int ts[256];
    const int t = threadIdx.x;
    const int base = blockIdx.x * 1024 + t * 4;
    int v0 = (base + 0 < N) ? deg[base + 0] : 0;
    int v1 = (base + 1 < N) ? deg[base + 1] : 0;
    int v2 = (base + 2 < N) ? deg[base + 2] : 0;
    int v3 = (base + 3 < N) ? deg[base + 3] : 0;
    int s = v0 + v1 + v2 + v3;
    ts[t] = s;
    __syncthreads();
    for (int o = 1; o < 256; o <<= 1) {
        int y = (t >= o) ? ts[t - o] : 0;
        __syncthreads();
        ts[t] += y;
        __syncthreads();
    }
    int excl = ts[t] - s;
    if (base + 0 < N) off[base + 0] = excl;
    if (base + 1 < N) off[base + 1] = excl + v0;
    if (base + 2 < N) off[base + 2] = excl + v0 + v1;
    if (base + 3 < N) off[base + 3] = excl + v0 + v1 + v2;
    if (t == 255) partials[blockIdx.x] = ts[255];
}

__global__ void k_scanB(int* __restrict__ partials, int nb) {
    __shared__ int ps[256];
    const int t = threadIdx.x;
    int v = (t < nb) ? partials[t] : 0;
    ps[t] = v;
    __syncthreads();
    for (int o = 1; o < 256; o <<= 1) {
        int y = (t >= o) ? ps[t - o] : 0;
        __syncthreads();
        ps[t] += y;
        __syncthreads();
    }
    if (t < nb) partials[t] = ps[t] - v;
}

__global__ void k_scanC(int* __restrict__ off, const int* __restrict__ partials, int N, int E) {
    const int t = threadIdx.x;
    const int base = blockIdx.x * 1024 + t * 4;
    const int add = partials[blockIdx.x];
#pragma unroll
    for (int q = 0; q < 4; ++q) {
        int idx = base + q;
        if (idx < N) off[idx] += add;
    }
    if (blockIdx.x == 0 && t == 0) off[N] = E;
}

// ---------------- column-scan per-block counts -> per-block cursors ----------------
__global__ void k_colscan(int* __restrict__ scratch, const int* __restrict__ off,
                          int NBINS, int N) {
    int g = blockIdx.x * blockDim.x + threadIdx.x;
    if (g >= NBINS) return;
    const int c = g >> 15;
    const int p = g & (HCHUNK - 1);
    int* col = scratch + ((size_t)(c * HBLK)) * HCHUNK + p;
    int run = (g < N) ? off[g] : 0;
    for (int b = 0; b < HBLK; ++b) {
        int* q = col + (size_t)b * HCHUNK;
        int t = *q;
        *q = run;
        run += t;
    }
}

// ---------------- atomic-free(global) CSR fill via LDS cursors ----------------
__global__ __launch_bounds__(512, 1)
void k_csrfill2(const int* __restrict__ src, const int* __restrict__ dst,
                const int* __restrict__ scratch, int* __restrict__ csr, int E) {
    __shared__ int cur[HCHUNK];   // 128 KiB
    const int c = blockIdx.x / HBLK;
    const int b = blockIdx.x % HBLK;
    const int base = c * HCHUNK;
    const int* my = scratch + (size_t)(c * HBLK + b) * HCHUNK;
    for (int i = threadIdx.x; i < HCHUNK; i += 512) cur[i] = my[i];
    __syncthreads();
    for (int i = b * 512 + threadIdx.x; i < E; i += HBLK * 512) {
        unsigned k = (unsigned)(dst[i] - base);
        if (k < HCHUNK) {
            int p = atomicAdd(&cur[k], 1);
            csr[p] = src[i];
        }
    }
}

// ---------------- MFMA split-bf16 GEMM:  M = pre(X) @ W, fp16 message output ----------------
// pre: PRE==0: x*dinv_src ; PRE==1: lrelu(x*dinv_dst + bias)*dinv_src
template <int PRE>
__global__ __launch_bounds__(512, 1)
void k_gemm_mfma(const float* __restrict__ X, __half* __restrict__ Y,
                 const unsigned short* __restrict__ whiT, const unsigned short* __restrict__ wloT,
                 const float* __restrict__ bias, const float* __restrict__ dinv_dst,
                 const float* __restrict__ dinv_src, int N) {
    __shared__ unsigned short Xhi[128 * 128];  // 32 KiB each
    __shared__ unsigned short Xlo[128 * 128];
    __shared__ unsigned short Whi[128 * 128];  // transposed+swizzled: [col][k^((col&31)<<2)]
    __shared__ unsigned short Wlo[128 * 128];
    const int t = threadIdx.x;
    const int r0 = blockIdx.x * 128;

    for (int i = t; i < 2048; i += 512) ((float4*)Whi)[i] = ((const float4*)whiT)[i];
    for (int i = t; i < 2048; i += 512) ((float4*)Wlo)[i] = ((const float4*)wloT)[i];

    for (int i = t; i < 4096; i += 512) {
        int row = i >> 5;
        int g4 = (i & 31) << 2;
        int grow = r0 + row;
        float4 v = make_float4(0.f, 0.f, 0.f, 0.f);
        if (grow < N) {
            v = ((const float4*)(X + (size_t)grow * 128))[i & 31];
            float ds = dinv_src[grow];
            if (PRE) {
                float dd = dinv_dst[grow];
                v.x = lrelu(v.x * dd + bias[g4 + 0]) * ds;
                v.y = lrelu(v.y * dd + bias[g4 + 1]) * ds;
                v.z = lrelu(v.z * dd + bias[g4 + 2]) * ds;
                v.w = lrelu(v.w * dd + bias[g4 + 3]) * ds;
            } else {
                v.x *= ds; v.y *= ds; v.z *= ds; v.w *= ds;
            }
        }
        unsigned short h0 = f2bf(v.x), h1 = f2bf(v.y), h2 = f2bf(v.z), h3 = f2bf(v.w);
        unsigned short l0 = f2bf(v.x - bf2f(h0)), l1 = f2bf(v.y - bf2f(h1));
        unsigned short l2 = f2bf(v.z - bf2f(h2)), l3 = f2bf(v.w - bf2f(h3));
        int ks = row * 128 + (g4 ^ ((row & 31) << 2));
        Xhi[ks + 0] = h0; Xhi[ks + 1] = h1; Xhi[ks + 2] = h2; Xhi[ks + 3] = h3;
        Xlo[ks + 0] = l0; Xlo[ks + 1] = l1; Xlo[ks + 2] = l2; Xlo[ks + 3] = l3;
    }
    __syncthreads();

    const int w = t >> 6;
    const int wm = w & 3;
    const int wn = w >> 2;
    const int lane = t & 63;
    const int lr = lane & 15;
    const int lg = lane >> 4;

    f32x4 acc[2][4];
#pragma unroll
    for (int mi = 0; mi < 2; ++mi)
#pragma unroll
        for (int ni = 0; ni < 4; ++ni) acc[mi][ni] = (f32x4){0.f, 0.f, 0.f, 0.f};

#pragma unroll
    for (int ks = 0; ks < 4; ++ks) {
        const int k0 = 32 * ks + 4 * lg;
        bf16x8 ah[2], al[2];
#pragma unroll
        for (int mi = 0; mi < 2; ++mi) {
            int row = 32 * wm + 16 * mi + lr;
            int sw = (row & 31) << 2;
            int o1 = row * 128 + (k0 ^ sw);
            int o2 = row * 128 + ((k0 + 16) ^ sw);
            union { uint4 u; bf16x8 v; } uh, ul;
            uh.u.x = *(const unsigned*)&Xhi[o1];     uh.u.y = *(const unsigned*)&Xhi[o1 + 2];
            uh.u.z = *(const unsigned*)&Xhi[o2];     uh.u.w = *(const unsigned*)&Xhi[o2 + 2];
            ul.u.x = *(const unsigned*)&Xlo[o1];     ul.u.y = *(const unsigned*)&Xlo[o1 + 2];
            ul.u.z = *(const unsigned*)&Xlo[o2];     ul.u.w = *(const unsigned*)&Xlo[o2 + 2];
            ah[mi] = uh.v; al[mi] = ul.v;
        }
#pragma unroll
        for (int ni = 0; ni < 4; ++ni) {
            int colv = 64 * wn + 16 * ni + lr;
            int sw = (colv & 31) << 2;
            int o1 = colv * 128 + (k0 ^ sw);
            int o2 = colv * 128 + ((k0 + 16) ^ sw);
            union { uint4 u; bf16x8 v; } bh, bl;
            bh.u.x = *(const unsigned*)&Whi[o1];     bh.u.y = *(const unsigned*)&Whi[o1 + 2];
            bh.u.z = *(const unsigned*)&Whi[o2];     bh.u.w = *(const unsigned*)&Whi[o2 + 2];
            bl.u.x = *(const unsigned*)&Wlo[o1];     bl.u.y = *(const unsigned*)&Wlo[o1 + 2];
            bl.u.z = *(const unsigned*)&Wlo[o2];     bl.u.w = *(const unsigned*)&Wlo[o2 + 2];
#pragma unroll
            for (int mi = 0; mi < 2; ++mi) {
                acc[mi][ni] = __builtin_amdgcn_mfma_f32_16x16x32_bf16(ah[mi], bh.v, acc[mi][ni], 0, 0, 0);
                acc[mi][ni] = __builtin_amdgcn_mfma_f32_16x16x32_bf16(ah[mi], bl.v, acc[mi][ni], 0, 0, 0);
                acc[mi][ni] = __builtin_amdgcn_mfma_f32_16x16x32_bf16(al[mi], bh.v, acc[mi][ni], 0, 0, 0);
            }
        }
    }

#pragma unroll
    for (int mi = 0; mi < 2; ++mi) {
#pragma unroll
        for (int r = 0; r < 4; ++r) {
            int row = r0 + 32 * wm + 16 * mi + 4 * lg + r;
            if (row < N) {
#pragma unroll
                for (int ni = 0; ni < 4; ++ni) {
                    Y[(size_t)row * 128 + 64 * wn + 16 * ni + lr] = __float2half(acc[mi][ni][r]);
                }
            }
        }
    }
}

// ---------------- CSR gather-aggregate (fp16 msgs): AGG[n] = sum T[src[e]] ----------------
__global__ __launch_bounds__(256)
void k_gather_h(const __half* __restrict__ T, float* __restrict__ Y,
                const int* __restrict__ csr, const int* __restrict__ off, int N) {
    int n = blockIdx.x * 8 + (threadIdx.x >> 5);
    if (n >= N) return;
    const int lane = threadIdx.x & 31;
    const int c = lane << 2;      // 4 halfs per lane (8 B)
    int j = off[n];
    const int jend = off[n + 1];
    float4 a0 = make_float4(0.f, 0.f, 0.f, 0.f);
    float4 a1 = make_float4(0.f, 0.f, 0.f, 0.f);
    union H4 { float2 raw; __half2 h[2]; };
    for (; j + 4 <= jend; j += 4) {
        int i0 = csr[j], i1 = csr[j + 1], i2 = csr[j + 2], i3 = csr[j + 3];
        H4 v0, v1, v2, v3;
        v0.raw = *(const float2*)(T + (size_t)i0 * 128 + c);
        v1.raw = *(const float2*)(T + (size_t)i1 * 128 + c);
        v2.raw = *(const float2*)(T + (size_t)i2 * 128 + c);
        v3.raw = *(const float2*)(T + (size_t)i3 * 128 + c);
        float2 x0 = __half22float2(v0.h[0]), y0 = __half22float2(v0.h[1]);
        float2 x1 = __half22float2(v1.h[0]), y1 = __half22float2(v1.h[1]);
        float2 x2 = __half22float2(v2.h[0]), y2 = __half22float2(v2.h[1]);
        float2 x3 = __half22float2(v3.h[0]), y3 = __half22float2(v3.h[1]);
        a0.x += x0.x + x1.x; a0.y += x0.y + x1.y; a0.z += y0.x + y1.x; a0.w += y0.y + y1.y;
        a1.x += x2.x + x3.x; a1.y += x2.y + x3.y; a1.z += y2.x + y3.x; a1.w += y2.y + y3.y;
    }
    for (; j < jend; ++j) {
        int i0 = csr[j];
        H4 v0;
        v0.raw = *(const float2*)(T + (size_t)i0 * 128 + c);
        float2 x0 = __half22float2(v0.h[0]), y0 = __half22float2(v0.h[1]);
        a0.x += x0.x; a0.y += x0.y; a0.z += y0.x; a0.w += y0.y;
    }
    float4 r = make_float4(a0.x + a1.x, a0.y + a1.y, a0.z + a1.z, a0.w + a1.w);
    *(float4*)(Y + (size_t)n * 128 + c) = r;
}

// ---------------- folded conv3+readout ----------------
__global__ void k_node_scalar(const float* __restrict__ A, const float* __restrict__ dinv_dst,
                              const float* __restrict__ dinv_src, const float* __restrict__ bias,
                              const float* __restrict__ w, float* __restrict__ tv, int N) {
    int gtid = blockIdx.x * blockDim.x + threadIdx.x;
    int wid = gtid >> 6;
    int lane = gtid & 63;
    if (wid >= N) return;
    float dd = dinv_dst[wid];
    const float* row = A + (size_t)wid * 128;
    float h0 = lrelu(row[lane] * dd + bias[lane]);
    float h1 = lrelu(row[lane + 64] * dd + bias[lane + 64]);
    float s = h0 * w[lane] + h1 * w[lane + 64];
#pragma unroll
    for (int o = 32; o > 0; o >>= 1) s += __shfl_down(s, o);
    if (lane == 0) tv[wid] = s * dinv_src[wid];
}

// ---------------- final: z[n]=sum tv[csr], s=z*ddst+c, per-graph mean bins ----------------
__global__ void k_gather_final(const float* __restrict__ tv, const int* __restrict__ csr,
                               const int* __restrict__ off, const float* __restrict__ ddst,
                               const int* __restrict__ gid, const float* __restrict__ cval,
                               float* __restrict__ gsum, float* __restrict__ gcnt, int N) {
    __shared__ float sb[N_GRAPHS], sc[N_GRAPHS];
    for (int i = threadIdx.x; i < N_GRAPHS; i += blockDim.x) { sb[i] = 0.f; sc[i] = 0.f; }
    __syncthreads();
    int n = blockIdx.x * blockDim.x + threadIdx.x;
    if (n < N) {
        int j = off[n], jend = off[n + 1];
        float z = 0.f;
        for (; j < jend; ++j) z += tv[csr[j]];
        float s = z * ddst[n] + cval[0];
        int g = gid[n];
        atomicAdd(&sb[g], s);
        atomicAdd(&sc[g], 1.f);
    }
    __syncthreads();
    for (int j = threadIdx.x; j < N_GRAPHS; j += blockDim.x) {
        if (sc[j] != 0.f) {
            atomicAdd(&gsum[j], sb[j]);
            atomicAdd(&gcnt[j], sc[j]);
        }
    }
}

__global__ void k_final(const float* __restrict__ gsum, const float* __restrict__ gcnt,
                        float* __restrict__ out) {
    int g = threadIdx.x;
    if (g < N_GRAPHS) out[g] = gsum[g] / fmaxf(gcnt[g], 1.0f);
}

extern "C" void kernel_launch(void* const* d_in, const int* in_sizes, int n_in,
                              void* d_out, int out_size, void* d_ws, size_t ws_size,
                              hipStream_t stream) {
    const float* in_feat = (const float*)d_in[0];
    const float* W1   = (const float*)d_in[1];
    const float* b1   = (const float*)d_in[2];
    const float* W2   = (const float*)d_in[3];
    const float* b2   = (const float*)d_in[4];
    const float* W3   = (const float*)d_in[5];
    const float* b3   = (const float*)d_in[6];
    const float* Wout = (const float*)d_in[7];
    const float* bout = (const float*)d_in[8];
    const int* src = (const int*)d_in[9];
    const int* dst = (const int*)d_in[10];
    const int* gid = (const int*)d_in[11];
    const int N = in_sizes[0] / 128;
    const int E = in_sizes[9];
    float* out = (float*)d_out;

    char* ws = (char*)d_ws;
    size_t woff = 0;
    auto alloc = [&](size_t bytes) {
        void* p = ws + woff;
        woff = (woff + bytes + 255) & ~(size_t)255;
        return p;
    };
    const int nchunks = (N + HCHUNK - 1) / HCHUNK;         // 4 for N=100000
    const int NBINS = nchunks * HCHUNK;
    size_t scratch_bytes = (size_t)NBINS * HBLK * 4;       // 33.5 MB
    size_t msg_bytes = (size_t)N * 128 * 2;                // 25.6 MB
    // M (fp16 messages) aliases histogram scratch: scratch is dead after k_csrfill2,
    // M's first write (gemm1) comes after.
    void* region0 = alloc(scratch_bytes > msg_bytes ? scratch_bytes : msg_bytes);
    int*    scratch = (int*)region0;
    __half* M       = (__half*)region0;
    float* AGG   = (float*)alloc((size_t)N * 128 * 4);
    int*   csr   = (int*)alloc((size_t)E * 4);
    int*   degd  = (int*)alloc((size_t)N * 4);
    int*   off   = (int*)alloc((size_t)(N + 1) * 4);
    int*   partials = (int*)alloc(256 * 4);
    float* dsrc  = (float*)alloc((size_t)N * 4);
    float* ddst  = (float*)alloc((size_t)N * 4);
    float* tv    = (float*)alloc((size_t)N * 4);
    float* wfold = (float*)alloc(128 * 4);
    float* cval  = (float*)alloc(4);
    float* gsum  = (float*)alloc(N_GRAPHS * 4);
    float* gcnt  = (float*)alloc(N_GRAPHS * 4);
    unsigned short* w1hi = (unsigned short*)alloc(16384 * 2);
    unsigned short* w1lo = (unsigned short*)alloc(16384 * 2);
    unsigned short* w2hi = (unsigned short*)alloc(16384 * 2);
    unsigned short* w2lo = (unsigned short*)alloc(16384 * 2);
    (void)ws_size; (void)n_in; (void)out_size;

    hipMemsetAsync(gsum, 0, N_GRAPHS * 4, stream);
    hipMemsetAsync(gcnt, 0, N_GRAPHS * 4, stream);

    k_fold_w<<<1, 128, 0, stream>>>(W3, b3, Wout, bout, wfold, cval);
    k_wsplit<<<1, 256, 0, stream>>>(W1, w1hi, w1lo);
    k_wsplit<<<1, 256, 0, stream>>>(W2, w2hi, w2lo);

    // degrees via chunked LDS histograms (no global atomics)
    k_hist<<<nchunks * HBLK, 512, 0, stream>>>(src, scratch, E);
    k_hist_reduce<0><<<(N + 255) / 256, 256, 0, stream>>>(scratch, nullptr, dsrc, N);
    k_hist<<<nchunks * HBLK, 512, 0, stream>>>(dst, scratch, E);
    k_hist_reduce<1><<<(N + 255) / 256, 256, 0, stream>>>(scratch, degd, ddst, N);

    // CSR offsets
    const int nscan = (N + 1023) / 1024;
    k_scanA<<<nscan, 256, 0, stream>>>(degd, off, partials, N);
    k_scanB<<<1, 256, 0, stream>>>(partials, nscan);
    k_scanC<<<nscan, 256, 0, stream>>>(off, partials, N, E);

    // per-block cursors, then counting-sort fill (LDS atomics only)
    k_colscan<<<(NBINS + 255) / 256, 256, 0, stream>>>(scratch, off, NBINS, N);
    k_csrfill2<<<nchunks * HBLK, 512, 0, stream>>>(src, dst, scratch, csr, E);

    const int gblocks = (N + 127) / 128;
    const int agblocks = (N + 7) / 8;

    // layer 1: M = (in_feat * dsrc) @ W1 ; AGG = gather(M)
    k_gemm_mfma<0><<<gblocks, 512, 0, stream>>>(in_feat, M, w1hi, w1lo, nullptr, nullptr, dsrc, N);
    k_gather_h<<<agblocks, 256, 0, stream>>>(M, AGG, csr, off, N);

    // layer 2: M = (lrelu(AGG*ddst + b1) * dsrc) @ W2 ; AGG = gather(M)
    k_gemm_mfma<1><<<gblocks, 512, 0, stream>>>(AGG, M, w2hi, w2lo, b1, ddst, dsrc, N);
    k_gather_h<<<agblocks, 256, 0, stream>>>(M, AGG, csr, off, N);

    // layer 3 (conv2 again): M = (lrelu(AGG*ddst + b2) * dsrc) @ W2 ; AGG = gather(M)
    k_gemm_mfma<1><<<gblocks, 512, 0, stream>>>(AGG, M, w2hi, w2lo, b2, ddst, dsrc, N);
    k_gather_h<<<agblocks, 256, 0, stream>>>(M, AGG, csr, off, N);

    // folded conv3 + readout
    k_node_scalar<<<(N + 3) / 4, 256, 0, stream>>>(AGG, ddst, dsrc, b2, wfold, tv, N);
    k_gather_final<<<(N + 255) / 256, 256, 0, stream>>>(tv, csr, off, ddst, gid, cval, gsum, gcnt, N);
    k_final<<<1, 128, 0, stream>>>(gsum, gcnt, out);
}

// Round 6
// 427.661 us; speedup vs baseline: 20.2099x; 1.1765x over previous
//
#include <hip/hip_runtime.h>
#include <hip/hip_fp16.h>
#include <math.h>

#define N_GRAPHS 100
#define HCHUNK 32768
#define HBLK 64

typedef _Float16 f16x8 __attribute__((ext_vector_type(8)));
typedef __attribute__((ext_vector_type(4))) float f32x4;

__device__ __forceinline__ float lrelu(float v) { return v >= 0.f ? v : 0.1f * v; }

// ---------------- chunked LDS histogram: per-block counts to scratch ----------------
__global__ __launch_bounds__(512, 1)
void k_hist(const int* __restrict__ keys, int* __restrict__ scratch, int E) {
    __shared__ int h[HCHUNK];   // 128 KiB
    const int c = blockIdx.x / HBLK;
    const int b = blockIdx.x % HBLK;
    const int base = c * HCHUNK;
    for (int i = threadIdx.x; i < HCHUNK; i += 512) h[i] = 0;
    __syncthreads();
    for (int i = b * 512 + threadIdx.x; i < E; i += HBLK * 512) {
        unsigned k = (unsigned)(keys[i] - base);
        if (k < HCHUNK) atomicAdd(&h[k], 1);
    }
    __syncthreads();
    int* outp = scratch + (size_t)blockIdx.x * HCHUNK;
    for (int i = threadIdx.x; i < HCHUNK; i += 512) outp[i] = h[i];
}

template <int WRITE_INT>
__global__ void k_hist_reduce(const int* __restrict__ scratch, int* __restrict__ deg_out,
                              float* __restrict__ dinv_out, int N) {
    int g = blockIdx.x * blockDim.x + threadIdx.x;
    if (g >= N) return;
    const int c = g >> 15;
    const int p = g & (HCHUNK - 1);
    const int* col = scratch + ((size_t)(c * HBLK)) * HCHUNK + p;
    int s = 0;
#pragma unroll 8
    for (int b = 0; b < HBLK; ++b) s += col[(size_t)b * HCHUNK];
    if (WRITE_INT) deg_out[g] = s;
    dinv_out[g] = rsqrtf(fmaxf((float)s, 1.0f));
}

// ---------------- fold W3 @ Wout -> w[128], c = b3.Wout + bout ----------------
__global__ void k_fold_w(const float* __restrict__ W3, const float* __restrict__ b3,
                         const float* __restrict__ Wout, const float* __restrict__ bout,
                         float* __restrict__ w, float* __restrict__ cval) {
    int i = threadIdx.x; // 128 threads
    float s = 0.f;
    for (int j = 0; j < 64; ++j) s += W3[i * 64 + j] * Wout[j];
    w[i] = s;
    if (i == 0) {
        float c = bout[0];
        for (int j = 0; j < 64; ++j) c += b3[j] * Wout[j];
        *cval = c;
    }
}

// ---------------- convert W (128x128 fp32) -> transposed+swizzled fp16 ----------------
// wT[col*128 + (k ^ ((col&31)<<2))] = fp16(W[k][col])
__global__ void k_wconv(const float* __restrict__ W, __half* __restrict__ wT) {
    int t = threadIdx.x;
    for (int i = t; i < 16384; i += 256) {
        int k = i >> 7, col = i & 127;
        wT[col * 128 + (k ^ ((col & 31) << 2))] = __float2half(W[i]);
    }
}

// ---------------- exclusive scan over degd -> off (3-kernel) ----------------
__global__ void k_scanA(const int* __restrict__ deg, int* __restrict__ off,
                        int* __restrict__ partials, int N) {
    __shared__ int ts[256];
    const int t = threadIdx.x;
    const int base = blockIdx.x * 1024 + t * 4;
    int v0 = (base + 0 < N) ? deg[base + 0] : 0;
    int v1 = (base + 1 < N) ? deg[base + 1] : 0;
    int v2 = (base + 2 < N) ? deg[base + 2] : 0;
    int v3 = (base + 3 < N) ? deg[base + 3] : 0;
    int s = v0 + v1 + v2 + v3;
    ts[t] = s;
    __syncthreads();
    for (int o = 1; o < 256; o <<= 1) {
        int y = (t >= o) ? ts[t - o] : 0;
        __syncthreads();
        ts[t] += y;
        __syncthreads();
    }
    int excl = ts[t] - s;
    if (base + 0 < N) off[base + 0] = excl;
    if (base + 1 < N) off[base + 1] = excl + v0;
    if (base + 2 < N) off[base + 2] = excl + v0 + v1;
    if (base + 3 < N) off[base + 3] = excl + v0 + v1 + v2;
    if (t == 255) partials[blockIdx.x] = ts[255];
}

__global__ void k_scanB(int* __restrict__ partials, int nb) {
    __shared__ int ps[256];
    const int t = threadIdx.x;
    int v = (t < nb) ? partials[t] : 0;
    ps[t] = v;
    __syncthreads();
    for (int o = 1; o < 256; o <<= 1) {
        int y = (t >= o) ? ps[t - o] : 0;
        __syncthreads();
        ps[t] += y;
        __syncthreads();
    }
    if (t < nb) partials[t] = ps[t] - v;
}

__global__ void k_scanC(int* __restrict__ off, const int* __restrict__ partials, int N, int E) {
    const int t = threadIdx.x;
    const int base = blockIdx.x * 1024 + t * 4;
    const int add = partials[blockIdx.x];
#pragma unroll
    for (int q = 0; q < 4; ++q) {
        int idx = base + q;
        if (idx < N) off[idx] += add;
    }
    if (blockIdx.x == 0 && t == 0) off[N] = E;
}

// ---------------- column-scan per-block counts -> per-block cursors ----------------
__global__ void k_colscan(int* __restrict__ scratch, const int* __restrict__ off,
                          int NBINS, int N) {
    int g = blockIdx.x * blockDim.x + threadIdx.x;
    if (g >= NBINS) return;
    const int c = g >> 15;
    const int p = g & (HCHUNK - 1);
    int* col = scratch + ((size_t)(c * HBLK)) * HCHUNK + p;
    int run = (g < N) ? off[g] : 0;
    for (int b = 0; b < HBLK; ++b) {
        int* q = col + (size_t)b * HCHUNK;
        int t = *q;
        *q = run;
        run += t;
    }
}

// ---------------- atomic-free(global) CSR fill via LDS cursors ----------------
__global__ __launch_bounds__(512, 1)
void k_csrfill2(const int* __restrict__ src, const int* __restrict__ dst,
                const int* __restrict__ scratch, int* __restrict__ csr, int E) {
    __shared__ int cur[HCHUNK];   // 128 KiB
    const int c = blockIdx.x / HBLK;
    const int b = blockIdx.x % HBLK;
    const int base = c * HCHUNK;
    const int* my = scratch + (size_t)(c * HBLK + b) * HCHUNK;
    for (int i = threadIdx.x; i < HCHUNK; i += 512) cur[i] = my[i];
    __syncthreads();
    for (int i = b * 512 + threadIdx.x; i < E; i += HBLK * 512) {
        unsigned k = (unsigned)(dst[i] - base);
        if (k < HCHUNK) {
            int p = atomicAdd(&cur[k], 1);
            csr[p] = src[i];
        }
    }
}

// ---------------- single-pass fp16 MFMA GEMM:  M = pre(X) @ W ----------------
// pre: PRE==0: x*dinv_src ; PRE==1: lrelu(x*dinv_dst + bias)*dinv_src
// LDS: X fp16 32 KB + W fp16 32 KB -> 2 blocks/CU.
template <int PRE>
__global__ __launch_bounds__(512, 2)
void k_gemm_mfma(const float* __restrict__ X, __half* __restrict__ Y,
                 const __half* __restrict__ wT, const float* __restrict__ bias,
                 const float* __restrict__ dinv_dst, const float* __restrict__ dinv_src,
                 int N) {
    __shared__ __half Xs[128 * 128];  // 32 KiB, row-swizzled granules of 4
    __shared__ __half Ws[128 * 128];  // 32 KiB, transposed+swizzled (from k_wconv)
    const int t = threadIdx.x;
    const int r0 = blockIdx.x * 128;

    for (int i = t; i < 2048; i += 512) ((float4*)Ws)[i] = ((const float4*)wT)[i];

    for (int i = t; i < 4096; i += 512) {
        int row = i >> 5;
        int g4 = (i & 31) << 2;
        int grow = r0 + row;
        float4 v = make_float4(0.f, 0.f, 0.f, 0.f);
        if (grow < N) {
            v = ((const float4*)(X + (size_t)grow * 128))[i & 31];
            float ds = dinv_src[grow];
            if (PRE) {
                float dd = dinv_dst[grow];
                v.x = lrelu(v.x * dd + bias[g4 + 0]) * ds;
                v.y = lrelu(v.y * dd + bias[g4 + 1]) * ds;
                v.z = lrelu(v.z * dd + bias[g4 + 2]) * ds;
                v.w = lrelu(v.w * dd + bias[g4 + 3]) * ds;
            } else {
                v.x *= ds; v.y *= ds; v.z *= ds; v.w *= ds;
            }
        }
        int ks = row * 128 + (g4 ^ ((row & 31) << 2));
        union { float2 f; __half2 h[2]; } pk;
        pk.h[0] = __floats2half2_rn(v.x, v.y);
        pk.h[1] = __floats2half2_rn(v.z, v.w);
        *(float2*)&Xs[ks] = pk.f;
    }
    __syncthreads();

    const int w = t >> 6;
    const int wm = w & 3;          // rows 32*wm..+31
    const int wn = w >> 2;         // cols 64*wn..+63
    const int lane = t & 63;
    const int lr = lane & 15;
    const int lg = lane >> 4;

    f32x4 acc[2][4];
#pragma unroll
    for (int mi = 0; mi < 2; ++mi)
#pragma unroll
        for (int ni = 0; ni < 4; ++ni) acc[mi][ni] = (f32x4){0.f, 0.f, 0.f, 0.f};

#pragma unroll
    for (int ks = 0; ks < 4; ++ks) {
        const int k0 = 32 * ks + 4 * lg;
        union F { float2 f[2]; f16x8 v; };
        F a[2];
#pragma unroll
        for (int mi = 0; mi < 2; ++mi) {
            int row = 32 * wm + 16 * mi + lr;
            int sw = (row & 31) << 2;
            a[mi].f[0] = *(const float2*)&Xs[row * 128 + (k0 ^ sw)];
            a[mi].f[1] = *(const float2*)&Xs[row * 128 + ((k0 + 16) ^ sw)];
        }
#pragma unroll
        for (int ni = 0; ni < 4; ++ni) {
            int colv = 64 * wn + 16 * ni + lr;
            int sw = (colv & 31) << 2;
            F b;
            b.f[0] = *(const float2*)&Ws[colv * 128 + (k0 ^ sw)];
            b.f[1] = *(const float2*)&Ws[colv * 128 + ((k0 + 16) ^ sw)];
#pragma unroll
            for (int mi = 0; mi < 2; ++mi) {
                acc[mi][ni] = __builtin_amdgcn_mfma_f32_16x16x32_f16(a[mi].v, b.v, acc[mi][ni], 0, 0, 0);
            }
        }
    }

#pragma unroll
    for (int mi = 0; mi < 2; ++mi) {
#pragma unroll
        for (int r = 0; r < 4; ++r) {
            int row = r0 + 32 * wm + 16 * mi + 4 * lg + r;
            if (row < N) {
#pragma unroll
                for (int ni = 0; ni < 4; ++ni) {
                    Y[(size_t)row * 128 + 64 * wn + 16 * ni + lr] = __float2half(acc[mi][ni][r]);
                }
            }
        }
    }
}

// ---------------- CSR gather (fp16 msgs), one wave per node ----------------
// Halves of the wave take alternate edges of the SAME node (uniform trip count).
// EPI==0: write AGG row (fp32).  EPI==1: fused conv3+readout -> tv[n].
template <int EPI>
__global__ __launch_bounds__(256)
void k_gather_h(const __half* __restrict__ T, float* __restrict__ Y,
                const int* __restrict__ csr, const int* __restrict__ off, int N,
                const float* __restrict__ ddst, const float* __restrict__ bias,
                const float* __restrict__ wfold, const float* __restrict__ dsrc,
                float* __restrict__ tv) {
    int n = blockIdx.x * 4 + (threadIdx.x >> 6);
    if (n >= N) return;
    const int lane = threadIdx.x & 63;
    const int h = lane >> 5;      // half id: edge parity
    const int c = (lane & 31) << 2;  // 4 halfs per lane
    int j = off[n];
    const int jend = off[n + 1];
    float4 a0 = make_float4(0.f, 0.f, 0.f, 0.f);
    float4 a1 = make_float4(0.f, 0.f, 0.f, 0.f);
    union H4 { float2 raw; __half2 hh[2]; };
    for (; j + 8 <= jend; j += 8) {
        int e0 = csr[j + 0 + h], e1 = csr[j + 2 + h], e2 = csr[j + 4 + h], e3 = csr[j + 6 + h];
        H4 v0, v1, v2, v3;
        v0.raw = *(const float2*)(T + (size_t)e0 * 128 + c);
        v1.raw = *(const float2*)(T + (size_t)e1 * 128 + c);
        v2.raw = *(const float2*)(T + (size_t)e2 * 128 + c);
        v3.raw = *(const float2*)(T + (size_t)e3 * 128 + c);
        float2 x0 = __half22float2(v0.hh[0]), y0 = __half22float2(v0.hh[1]);
        float2 x1 = __half22float2(v1.hh[0]), y1 = __half22float2(v1.hh[1]);
        float2 x2 = __half22float2(v2.hh[0]), y2 = __half22float2(v2.hh[1]);
        float2 x3 = __half22float2(v3.hh[0]), y3 = __half22float2(v3.hh[1]);
        a0.x += x0.x + x1.x; a0.y += x0.y + x1.y; a0.z += y0.x + y1.x; a0.w += y0.y + y1.y;
        a1.x += x2.x + x3.x; a1.y += x2.y + x3.y; a1.z += y2.x + y3.x; a1.w += y2.y + y3.y;
    }
    for (; j + 2 <= jend; j += 2) {
        int e0 = csr[j + h];
        H4 v0;
        v0.raw = *(const float2*)(T + (size_t)e0 * 128 + c);
        float2 x0 = __half22float2(v0.hh[0]), y0 = __half22float2(v0.hh[1]);
        a0.x += x0.x; a0.y += x0.y; a0.z += y0.x; a0.w += y0.y;
    }
    if (j < jend && h == 0) {
        int e0 = csr[j];
        H4 v0;
        v0.raw = *(const float2*)(T + (size_t)e0 * 128 + c);
        float2 x0 = __half22float2(v0.hh[0]), y0 = __half22float2(v0.hh[1]);
        a0.x += x0.x; a0.y += x0.y; a0.z += y0.x; a0.w += y0.y;
    }
    float4 a = make_float4(a0.x + a1.x, a0.y + a1.y, a0.z + a1.z, a0.w + a1.w);
    // cross-half merge (lane L and L+32 hold same columns)
    a.x += __shfl_xor(a.x, 32);
    a.y += __shfl_xor(a.y, 32);
    a.z += __shfl_xor(a.z, 32);
    a.w += __shfl_xor(a.w, 32);
    if (EPI == 0) {
        if (h == 0) *(float4*)(Y + (size_t)n * 128 + c) = a;
    } else {
        if (h == 0) {
            float dd = ddst[n];
            float s = lrelu(a.x * dd + bias[c + 0]) * wfold[c + 0]
                    + lrelu(a.y * dd + bias[c + 1]) * wfold[c + 1]
                    + lrelu(a.z * dd + bias[c + 2]) * wfold[c + 2]
                    + lrelu(a.w * dd + bias[c + 3]) * wfold[c + 3];
#pragma unroll
            for (int o = 16; o > 0; o >>= 1) s += __shfl_xor(s, o);
            if ((lane & 31) == 0) tv[n] = s * dsrc[n];
        }
    }
}

// ---------------- final: z[n]=sum tv[csr], s=z*ddst+c, per-graph mean bins ----------------
__global__ void k_gather_final(const float* __restrict__ tv, const int* __restrict__ csr,
                               const int* __restrict__ off, const float* __restrict__ ddst,
                               const int* __restrict__ gid, const float* __restrict__ cval,
                               float* __restrict__ gsum, float* __restrict__ gcnt, int N) {
    __shared__ float sb[N_GRAPHS], sc[N_GRAPHS];
    for (int i = threadIdx.x; i < N_GRAPHS; i += blockDim.x) { sb[i] = 0.f; sc[i] = 0.f; }
    __syncthreads();
    int n = blockIdx.x * blockDim.x + threadIdx.x;
    if (n < N) {
        int j = off[n], jend = off[n + 1];
        float z = 0.f;
        for (; j < jend; ++j) z += tv[csr[j]];
        float s = z * ddst[n] + cval[0];
        int g = gid[n];
        atomicAdd(&sb[g], s);
        atomicAdd(&sc[g], 1.f);
    }
    __syncthreads();
    for (int j = threadIdx.x; j < N_GRAPHS; j += blockDim.x) {
        if (sc[j] != 0.f) {
            atomicAdd(&gsum[j], sb[j]);
            atomicAdd(&gcnt[j], sc[j]);
        }
    }
}

__global__ void k_final(const float* __restrict__ gsum, const float* __restrict__ gcnt,
                        float* __restrict__ out) {
    int g = threadIdx.x;
    if (g < N_GRAPHS) out[g] = gsum[g] / fmaxf(gcnt[g], 1.0f);
}

extern "C" void kernel_launch(void* const* d_in, const int* in_sizes, int n_in,
                              void* d_out, int out_size, void* d_ws, size_t ws_size,
                              hipStream_t stream) {
    const float* in_feat = (const float*)d_in[0];
    const float* W1   = (const float*)d_in[1];
    const float* b1   = (const float*)d_in[2];
    const float* W2   = (const float*)d_in[3];
    const float* b2   = (const float*)d_in[4];
    const float* W3   = (const float*)d_in[5];
    const float* b3   = (const float*)d_in[6];
    const float* Wout = (const float*)d_in[7];
    const float* bout = (const float*)d_in[8];
    const int* src = (const int*)d_in[9];
    const int* dst = (const int*)d_in[10];
    const int* gid = (const int*)d_in[11];
    const int N = in_sizes[0] / 128;
    const int E = in_sizes[9];
    float* out = (float*)d_out;

    char* ws = (char*)d_ws;
    size_t woff = 0;
    auto alloc = [&](size_t bytes) {
        void* p = ws + woff;
        woff = (woff + bytes + 255) & ~(size_t)255;
        return p;
    };
    const int nchunks = (N + HCHUNK - 1) / HCHUNK;         // 4 for N=100000
    const int NBINS = nchunks * HCHUNK;
    size_t scratch_bytes = (size_t)NBINS * HBLK * 4;       // 33.5 MB
    size_t msg_bytes = (size_t)N * 128 * 2;                // 25.6 MB
    // M (fp16 messages) aliases histogram scratch: scratch dead after k_csrfill2.
    void* region0 = alloc(scratch_bytes > msg_bytes ? scratch_bytes : msg_bytes);
    int*    scratch = (int*)region0;
    __half* M       = (__half*)region0;
    float* AGG   = (float*)alloc((size_t)N * 128 * 4);
    int*   csr   = (int*)alloc((size_t)E * 4);
    int*   degd  = (int*)alloc((size_t)N * 4);
    int*   off   = (int*)alloc((size_t)(N + 1) * 4);
    int*   partials = (int*)alloc(256 * 4);
    float* dsrc  = (float*)alloc((size_t)N * 4);
    float* ddst  = (float*)alloc((size_t)N * 4);
    float* tv    = (float*)alloc((size_t)N * 4);
    float* wfold = (float*)alloc(128 * 4);
    float* cval  = (float*)alloc(4);
    float* gsum  = (float*)alloc(N_GRAPHS * 4);
    float* gcnt  = (float*)alloc(N_GRAPHS * 4);
    __half* w1T  = (__half*)alloc(16384 * 2);
    __half* w2T  = (__half*)alloc(16384 * 2);
    (void)ws_size; (void)n_in; (void)out_size;

    hipMemsetAsync(gsum, 0, N_GRAPHS * 4, stream);
    hipMemsetAsync(gcnt, 0, N_GRAPHS * 4, stream);

    k_fold_w<<<1, 128, 0, stream>>>(W3, b3, Wout, bout, wfold, cval);
    k_wconv<<<1, 256, 0, stream>>>(W1, w1T);
    k_wconv<<<1, 256, 0, stream>>>(W2, w2T);

    // degrees via chunked LDS histograms (no global atomics)
    k_hist<<<nchunks * HBLK, 512, 0, stream>>>(src, scratch, E);
    k_hist_reduce<0><<<(N + 255) / 256, 256, 0, stream>>>(scratch, nullptr, dsrc, N);
    k_hist<<<nchunks * HBLK, 512, 0, stream>>>(dst, scratch, E);
    k_hist_reduce<1><<<(N + 255) / 256, 256, 0, stream>>>(scratch, degd, ddst, N);

    // CSR offsets
    const int nscan = (N + 1023) / 1024;
    k_scanA<<<nscan, 256, 0, stream>>>(degd, off, partials, N);
    k_scanB<<<1, 256, 0, stream>>>(partials, nscan);
    k_scanC<<<nscan, 256, 0, stream>>>(off, partials, N, E);

    // per-block cursors, then counting-sort fill (LDS atomics only)
    k_colscan<<<(NBINS + 255) / 256, 256, 0, stream>>>(scratch, off, NBINS, N);
    k_csrfill2<<<nchunks * HBLK, 512, 0, stream>>>(src, dst, scratch, csr, E);

    const int gblocks = (N + 127) / 128;
    const int agblocks = (N + 3) / 4;   // 1 wave per node

    // layer 1: M = (in_feat * dsrc) @ W1 ; AGG = gather(M)
    k_gemm_mfma<0><<<gblocks, 512, 0, stream>>>(in_feat, M, w1T, nullptr, nullptr, dsrc, N);
    k_gather_h<0><<<agblocks, 256, 0, stream>>>(M, AGG, csr, off, N, nullptr, nullptr, nullptr, nullptr, nullptr);

    // layer 2: M = (lrelu(AGG*ddst + b1) * dsrc) @ W2 ; AGG = gather(M)
    k_gemm_mfma<1><<<gblocks, 512, 0, stream>>>(AGG, M, w2T, b1, ddst, dsrc, N);
    k_gather_h<0><<<agblocks, 256, 0, stream>>>(M, AGG, csr, off, N, nullptr, nullptr, nullptr, nullptr, nullptr);

    // layer 3 (conv2 again): M = (lrelu(AGG*ddst + b2) * dsrc) @ W2
    k_gemm_mfma<1><<<gblocks, 512, 0, stream>>>(AGG, M, w2T, b2, ddst, dsrc, N);
    // gather #3 fused with conv3+readout fold -> tv
    k_gather_h<1><<<agblocks, 256, 0, stream>>>(M, nullptr, csr, off, N, ddst, b2, wfold, dsrc, tv);

    // readout aggregation + per-graph mean
    k_gather_final<<<(N + 255) / 256, 256, 0, stream>>>(tv, csr, off, ddst, gid, cval, gsum, gcnt, N);
    k_final<<<1, 128, 0, stream>>>(gsum, gcnt, out);
}